// Round 5
// baseline (2972.883 us; speedup 1.0000x reference)
//
#include <hip/hip_runtime.h>
#include <stdint.h>

typedef __bf16 bf16x8 __attribute__((ext_vector_type(8)));
typedef float f32x4 __attribute__((ext_vector_type(4)));

__device__ __forceinline__ float bf2f(unsigned short u) {
    return __uint_as_float(((unsigned)u) << 16);
}
__device__ __forceinline__ unsigned short f2bf(float f) {
    unsigned u = __float_as_uint(f);
    unsigned r = u + 0x7fffu + ((u >> 16) & 1u);  // RNE
    return (unsigned short)(r >> 16);
}
__device__ __forceinline__ void unpack4(uint2 u, float& a, float& b, float& c, float& d) {
    a = __uint_as_float(u.x << 16);
    b = __uint_as_float(u.x & 0xffff0000u);
    c = __uint_as_float(u.y << 16);
    d = __uint_as_float(u.y & 0xffff0000u);
}
__device__ __forceinline__ uint2 pack4(float a, float b, float c, float d) {
    uint2 o;
    o.x = (unsigned)f2bf(a) | ((unsigned)f2bf(b) << 16);
    o.y = (unsigned)f2bf(c) | ((unsigned)f2bf(d) << 16);
    return o;
}

// ---------------- fused prep: cvt x -> bf16, transpose node_w, conv_w ----------------
// grid = [cvt blocks | tr_node blocks | tr_conv blocks]

__global__ void prep_kernel(const float* __restrict__ x, unsigned short* __restrict__ xbf, int nx4,
                            const float* __restrict__ nw, unsigned short* __restrict__ nwT,
                            const float* __restrict__ cw, unsigned short* __restrict__ cwT,
                            int b_cvt, int b_trn) {
    int b = blockIdx.x;
    if (b < b_cvt) {
        int i = (b * 256 + threadIdx.x) * 4;
        if (i < nx4 * 4) {
            float4 v = *reinterpret_cast<const float4*>(x + i);
            *reinterpret_cast<uint2*>(xbf + i) = pack4(v.x, v.y, v.z, v.w);
        }
    } else if (b < b_cvt + b_trn) {
        int idx = (b - b_cvt) * 256 + threadIdx.x;  // over 64*256
        int k = idx >> 8, n = idx & 255;
        nwT[n * 64 + k] = f2bf(nw[idx]);
    } else {
        int idx = (b - b_cvt - b_trn) * 256 + threadIdx.x;  // over 3*256*256
        int l = idx >> 16, rem = idx & 65535;
        int k = rem >> 8, n = rem & 255;
        cwT[(l << 16) + (n << 8) + k] = f2bf(cw[idx]);
    }
}

// ---------------- degree / CSR build ----------------

__global__ void deg_kernel(const int* __restrict__ col, int* __restrict__ cnt, int E) {
    int e = blockIdx.x * 256 + threadIdx.x;
    if (e < E) atomicAdd(&cnt[col[e]], 1);
}

__global__ void scan1_kernel(const int* __restrict__ cnt, int* __restrict__ scanbuf,
                             int* __restrict__ bsum, float* __restrict__ dis, int N) {
    __shared__ int s[512];
    int i = blockIdx.x * 512 + threadIdx.x;
    int c = (i < N) ? cnt[i] : 0;
    if (i < N) dis[i] = rsqrtf((float)c + 1.0f);  // +1 self-loop
    s[threadIdx.x] = c;
    __syncthreads();
    for (int off = 1; off < 512; off <<= 1) {
        int t = (threadIdx.x >= off) ? s[threadIdx.x - off] : 0;
        __syncthreads();
        s[threadIdx.x] += t;
        __syncthreads();
    }
    if (i < N) scanbuf[i] = s[threadIdx.x];
    if (threadIdx.x == 511) bsum[blockIdx.x] = s[511];
}

__global__ void scan2_kernel(const int* __restrict__ bsum, int* __restrict__ boff, int nb) {
    if (threadIdx.x == 0 && blockIdx.x == 0) {
        int acc = 0;
        for (int b = 0; b < nb; b++) { boff[b] = acc; acc += bsum[b]; }
    }
}

__global__ void scan3_kernel(const int* __restrict__ scanbuf, const int* __restrict__ boff,
                             int* __restrict__ rowstart, int N) {
    int i = blockIdx.x * 256 + threadIdx.x;
    if (i < N) rowstart[i + 1] = scanbuf[i] + boff[i >> 9];
    if (i == 0) rowstart[0] = 0;
}

__global__ void scatter_kernel(const int* __restrict__ row, const int* __restrict__ col,
                               const int* __restrict__ rowstart, int* __restrict__ fill,
                               int* __restrict__ eidx, unsigned char* __restrict__ tloc, int E) {
    int e = blockIdx.x * 256 + threadIdx.x;
    if (e < E) {
        int c = col[e];
        int pos = rowstart[c] + atomicAdd(&fill[c], 1);
        eidx[pos] = row[e];
        tloc[pos] = (unsigned char)(c & 15);
    }
}

__global__ void zrow_kernel(unsigned short* __restrict__ p) {
    p[threadIdx.x] = 0;  // 256-wide zero row
}

// ---------------- GEMM: C[M,Nc] = A[M,K] * B[K,Nc], B given transposed (BT[Nc,K]) ----------------

__global__ __launch_bounds__(256)
void gemm_bt_kernel(const unsigned short* __restrict__ A, const unsigned short* __restrict__ BT,
                    unsigned short* __restrict__ C, const float* __restrict__ bias,
                    const float* __restrict__ scale, int M, int K, int Nc) {
    const int lane = threadIdx.x & 63;
    const int wave = threadIdx.x >> 6;
    const int wm = wave >> 1, wn = wave & 1;
    const int r = lane & 15, q = lane >> 4;
    const int m0 = blockIdx.x * 128 + wm * 64;
    const int n0 = blockIdx.y * 128 + wn * 64;

    f32x4 acc[4][4] = {};

    for (int k0 = 0; k0 < K; k0 += 32) {
        bf16x8 a[4], b[4];
#pragma unroll
        for (int i = 0; i < 4; i++) {
            int mr = m0 + i * 16 + r;
            if (mr >= M) mr = M - 1;  // clamp; masked at store
            a[i] = *reinterpret_cast<const bf16x8*>(A + (size_t)mr * K + k0 + q * 8);
        }
#pragma unroll
        for (int j = 0; j < 4; j++) {
            int nr = n0 + j * 16 + r;
            b[j] = *reinterpret_cast<const bf16x8*>(BT + (size_t)nr * K + k0 + q * 8);
        }
#pragma unroll
        for (int i = 0; i < 4; i++)
#pragma unroll
            for (int j = 0; j < 4; j++)
                acc[i][j] = __builtin_amdgcn_mfma_f32_16x16x32_bf16(a[i], b[j], acc[i][j], 0, 0, 0);
    }

#pragma unroll
    for (int i = 0; i < 4; i++) {
#pragma unroll
        for (int t = 0; t < 4; t++) {
            int mr = m0 + i * 16 + q * 4 + t;  // C/D: row = q*4+reg, col = lane&15
            if (mr < M) {
                float rs = scale ? scale[mr] : 1.0f;
#pragma unroll
                for (int j = 0; j < 4; j++) {
                    int nc = n0 + j * 16 + r;
                    float v = acc[i][j][t] * rs;
                    if (bias) v += bias[nc];
                    C[(size_t)mr * Nc + nc] = f2bf(v);
                }
            }
        }
    }
}

// ---------------- aggregation: edge-parallel, LDS fp32 accumulators ----------------
// hws[v] = dis[v] * (h @ W)[v]; hws[N] is a zero row. Tiles of 16 nodes (N % 16 == 0
// for this problem, guards kept). Block = 256 thr = 8 half-waves. acc[17][256] fp32 in
// LDS (row 16 = junk for padded slots), initialized with the self rows. Each half-wave
// takes 4 contiguous edges per iteration (stride 32 per block), gathers uint4
// (8 feats/lane), atomicAdds into LDS. Feature f lives at LDS slot (f&7)*32+(f>>3)
// so the 32 lanes of a ds_add hit 32 distinct banks (conflict-free).
// Finalize: thread f owns feature f across the 16 nodes; writes bf16 agg + BN stats.

__global__ __launch_bounds__(256)
void agg_kernel(const unsigned short* __restrict__ hws, const int* __restrict__ rowstart,
                const int* __restrict__ eidx, const unsigned char* __restrict__ tloc,
                const float* __restrict__ dis, const float* __restrict__ cb,
                unsigned short* __restrict__ agg, float* __restrict__ stats, int N) {
    __shared__ float acc[17 * 256];
    __shared__ float sdv[16];
    const int tid = threadIdx.x;
    const int v0 = blockIdx.x * 16;
    const int l = tid & 31;
    const int fl = l * 8;

    // init accumulators with self rows (perm layout), zero junk row
    {
        const int vv = tid >> 5;  // 8 rows per pass
#pragma unroll
        for (int pass = 0; pass < 2; pass++) {
            int v = vv + pass * 8;
            int vr = min(v0 + v, N);
            uint4 rw = *reinterpret_cast<const uint4*>(hws + (size_t)vr * 256 + fl);
            float x[8];
            unpack4(make_uint2(rw.x, rw.y), x[0], x[1], x[2], x[3]);
            unpack4(make_uint2(rw.z, rw.w), x[4], x[5], x[6], x[7]);
            bool ok = (v0 + v) < N;
#pragma unroll
            for (int j = 0; j < 8; j++)
                acc[v * 256 + j * 32 + l] = ok ? x[j] : 0.0f;
        }
        acc[16 * 256 + tid] = 0.0f;
        if (tid < 16) sdv[tid] = (v0 + tid < N) ? dis[v0 + tid] : 0.0f;
    }
    __syncthreads();

    const int p0 = rowstart[v0];
    const int p1 = rowstart[min(v0 + 16, N)];
    const int hw_id = tid >> 5;

    int pb = p0 + hw_id * 4;
    int cidx[4], ctl[4];
#pragma unroll
    for (int k = 0; k < 4; k++) { cidx[k] = N; ctl[k] = 16; }
    if (pb < p1) {
#pragma unroll
        for (int k = 0; k < 4; k++) {
            int p = pb + k;
            int raw = eidx[p];          // eidx padded; masked below
            int rt = tloc[p];
            bool ok = p < p1;
            cidx[k] = ok ? raw : N;
            ctl[k] = ok ? rt : 16;
        }
    }

    for (; pb < p1; pb += 32) {
        int nidx[4], ntl[4];
#pragma unroll
        for (int k = 0; k < 4; k++) { nidx[k] = N; ntl[k] = 16; }
        int pn = pb + 32;
        if (pn < p1) {
#pragma unroll
            for (int k = 0; k < 4; k++) {
                int p = pn + k;
                int raw = eidx[p];
                int rt = tloc[p];
                bool ok = p < p1;
                nidx[k] = ok ? raw : N;
                ntl[k] = ok ? rt : 16;
            }
        }
        uint4 rw[4];
#pragma unroll
        for (int k = 0; k < 4; k++)
            rw[k] = *reinterpret_cast<const uint4*>(hws + (size_t)cidx[k] * 256 + fl);
#pragma unroll
        for (int k = 0; k < 4; k++) {
            float x[8];
            unpack4(make_uint2(rw[k].x, rw[k].y), x[0], x[1], x[2], x[3]);
            unpack4(make_uint2(rw[k].z, rw[k].w), x[4], x[5], x[6], x[7]);
            float* a = &acc[ctl[k] * 256];
#pragma unroll
            for (int j = 0; j < 8; j++) atomicAdd(&a[j * 32 + l], x[j]);
        }
#pragma unroll
        for (int k = 0; k < 4; k++) { cidx[k] = nidx[k]; ctl[k] = ntl[k]; }
    }
    __syncthreads();

    // finalize: thread f owns feature f
    const int f = tid;
    const int slot = ((f & 7) << 5) + (f >> 3);
    const float cbf = cb[f];
    float ps = 0.0f, pq = 0.0f;
#pragma unroll 4
    for (int v = 0; v < 16; v++) {
        if (v0 + v < N) {
            float g = cbf + sdv[v] * acc[v * 256 + slot];
            agg[(size_t)(v0 + v) * 256 + f] = f2bf(g);
            ps += g; pq += g * g;
        }
    }
    atomicAdd(&stats[f], ps);
    atomicAdd(&stats[256 + f], pq);
}

__global__ void bnfin_kernel(float* __restrict__ stats, const float* __restrict__ g,
                             const float* __restrict__ b, float* __restrict__ ss, int N) {
    int f = threadIdx.x;
    float inv_n = 1.0f / (float)N;
    float mean = stats[f] * inv_n;
    float var = stats[256 + f] * inv_n - mean * mean;
    float rstd = rsqrtf(var + 1e-5f);
    float sc = g[f] * rstd;
    ss[f] = sc;
    ss[256 + f] = b[f] - mean * sc;
    stats[f] = 0.0f;          // clear for next layer
    stats[256 + f] = 0.0f;
}

__global__ void elem_kernel(const unsigned short* __restrict__ agg, const float* __restrict__ ss,
                            unsigned short* __restrict__ h, size_t total) {
    size_t i = ((size_t)blockIdx.x * 256 + threadIdx.x) * 4;
    if (i < total) {
        float a0, a1, a2, a3;
        unpack4(*reinterpret_cast<const uint2*>(agg + i), a0, a1, a2, a3);
        int f = (int)(i & 255);
        float r0 = fmaxf(a0 * ss[f] + ss[256 + f], 0.0f);
        float r1 = fmaxf(a1 * ss[f + 1] + ss[256 + f + 1], 0.0f);
        float r2 = fmaxf(a2 * ss[f + 2] + ss[256 + f + 2], 0.0f);
        float r3 = fmaxf(a3 * ss[f + 3] + ss[256 + f + 3], 0.0f);
        *reinterpret_cast<uint2*>(h + i) = pack4(r0, r1, r2, r3);
    }
}

// ---------------- global_add_pool (batch is sorted) ----------------

__global__ __launch_bounds__(256)
void pool_kernel(const unsigned short* __restrict__ h, const int* __restrict__ batch,
                 float* __restrict__ g, int N) {
    __shared__ int sb[256];
    int f = threadIdx.x;
    int r0 = blockIdx.x * 256;
    int rows = min(256, N - r0);
    sb[f] = (r0 + f < N) ? batch[r0 + f] : -1;
    __syncthreads();
    float acc = 0.0f;
    int cur = sb[0];
    for (int t = 0; t < rows; t++) {
        int b = sb[t];
        if (b != cur) {
            atomicAdd(&g[cur * 256 + f], acc);
            acc = 0.0f;
            cur = b;
        }
        acc += bf2f(h[(size_t)(r0 + t) * 256 + f]);
    }
    atomicAdd(&g[cur * 256 + f], acc);
}

// ---------------- head MLP: relu(g@w1+b1)@w2+b2 ----------------

__global__ void head_kernel(const float* __restrict__ g, const float* __restrict__ w1,
                            const float* __restrict__ b1, const float* __restrict__ w2,
                            const float* __restrict__ b2, float* __restrict__ out) {
    __shared__ float gr[256];
    __shared__ float z[128];
    int b = blockIdx.x, t = threadIdx.x;
    gr[t] = g[b * 256 + t];
    gr[t + 128] = g[b * 256 + 128 + t];
    __syncthreads();
    float acc = b1[t];
    for (int k = 0; k < 256; k++) acc += gr[k] * w1[k * 128 + t];
    z[t] = fmaxf(acc, 0.0f);
    __syncthreads();
    if (t < 12) {
        float o = b2[t];
        for (int k = 0; k < 128; k++) o += z[k] * w2[k * 12 + t];
        out[b * 12 + t] = o;
    }
}

// ---------------- launch ----------------

extern "C" void kernel_launch(void* const* d_in, const int* in_sizes, int n_in,
                              void* d_out, int out_size, void* d_ws, size_t ws_size,
                              hipStream_t stream) {
    const float* x      = (const float*)d_in[0];
    const int*   ei     = (const int*)d_in[1];
    const int*   batch  = (const int*)d_in[2];
    const float* node_w = (const float*)d_in[3];
    const float* node_b = (const float*)d_in[4];
    const float* conv_w = (const float*)d_in[5];
    const float* conv_b = (const float*)d_in[6];
    const float* bn_g   = (const float*)d_in[7];
    const float* bn_b   = (const float*)d_in[8];
    const float* hw1    = (const float*)d_in[9];
    const float* hb1    = (const float*)d_in[10];
    const float* hw2    = (const float*)d_in[11];
    const float* hb2    = (const float*)d_in[12];
    float* out = (float*)d_out;

    const int N = in_sizes[2];
    const int E = in_sizes[1] / 2;
    const int IN = 64, H = 256, L = 3;

    char* base = (char*)d_ws;
    size_t off = 0;
    auto alloc = [&](size_t bytes) -> void* {
        off = (off + 255) & ~(size_t)255;
        void* p = base + off;
        off += bytes;
        return p;
    };
    unsigned short* xbf = (unsigned short*)alloc((size_t)N * IN * 2);
    unsigned short* h   = (unsigned short*)alloc((size_t)N * H * 2);
    unsigned short* hws = (unsigned short*)alloc((size_t)(N + 1) * H * 2);  // +1 zero row
    unsigned short* agg = (unsigned short*)alloc((size_t)N * H * 2);
    unsigned short* nwT = (unsigned short*)alloc((size_t)IN * H * 2);
    unsigned short* cwT = (unsigned short*)alloc((size_t)L * H * H * 2);
    int* cnt      = (int*)alloc((size_t)N * 4);
    int* fill     = (int*)alloc((size_t)N * 4);
    int* rowstart = (int*)alloc((size_t)(N + 1) * 4);
    int* scanbuf  = (int*)alloc((size_t)N * 4);
    int* bsum     = (int*)alloc(1024);
    int* boff     = (int*)alloc(1024);
    int* eidx     = (int*)alloc((size_t)(E + 64) * 4);            // +64 pad (OOB reads masked)
    unsigned char* tloc = (unsigned char*)alloc((size_t)(E + 64));
    float* dis    = (float*)alloc((size_t)N * 4);
    float* stats  = (float*)alloc(512 * 4);
    float* ss     = (float*)alloc(512 * 4);
    float* gpool  = (float*)alloc(64 * H * 4);

    const int* row = ei;
    const int* col = ei + E;

    hipMemsetAsync(cnt, 0, (size_t)N * 4, stream);
    hipMemsetAsync(fill, 0, (size_t)N * 4, stream);
    hipMemsetAsync(stats, 0, 512 * 4, stream);
    zrow_kernel<<<dim3(1), 256, 0, stream>>>(hws + (size_t)N * H);

    int b_cvt = (N * IN / 4 + 255) / 256;
    int b_trn = (IN * H) / 256;
    int b_trc = (L * H * H) / 256;
    prep_kernel<<<dim3(b_cvt + b_trn + b_trc), 256, 0, stream>>>(
        x, xbf, N * IN / 4, node_w, nwT, conv_w, cwT, b_cvt, b_trn);

    deg_kernel<<<dim3((E + 255) / 256), 256, 0, stream>>>(col, cnt, E);
    int nb = (N + 511) / 512;
    scan1_kernel<<<dim3(nb), 512, 0, stream>>>(cnt, scanbuf, bsum, dis, N);
    scan2_kernel<<<dim3(1), 64, 0, stream>>>(bsum, boff, nb);
    scan3_kernel<<<dim3((N + 255) / 256), 256, 0, stream>>>(scanbuf, boff, rowstart, N);
    scatter_kernel<<<dim3((E + 255) / 256), 256, 0, stream>>>(row, col, rowstart, fill, eidx, tloc, E);

    dim3 gg((N + 127) / 128, H / 128);
    gemm_bt_kernel<<<gg, 256, 0, stream>>>(xbf, nwT, h, node_b, nullptr, N, IN, H);

    for (int l = 0; l < L; l++) {
        // hws = dis[v] * (h @ conv_w[l])  (scale fused into epilogue)
        gemm_bt_kernel<<<gg, 256, 0, stream>>>(h, cwT + (size_t)l * H * H, hws, nullptr, dis, N, H, H);
        agg_kernel<<<dim3((N + 15) / 16), 256, 0, stream>>>(hws, rowstart, eidx, tloc, dis,
                                                            conv_b + l * H, agg, stats, N);
        bnfin_kernel<<<dim3(1), 256, 0, stream>>>(stats, bn_g + l * H, bn_b + l * H, ss, N);
        size_t total = (size_t)N * H;
        elem_kernel<<<dim3((int)((total / 4 + 255) / 256)), 256, 0, stream>>>(agg, ss, h, total);
    }

    hipMemsetAsync(gpool, 0, 64 * H * 4, stream);
    pool_kernel<<<dim3((N + 255) / 256), 256, 0, stream>>>(h, batch, gpool, N);
    head_kernel<<<dim3(64), 128, 0, stream>>>(gpool, hw1, hb1, hw2, hb2, out);
}

// Round 6
// 912.676 us; speedup vs baseline: 3.2573x; 3.2573x over previous
//
#include <hip/hip_runtime.h>
#include <stdint.h>

typedef __bf16 bf16x8 __attribute__((ext_vector_type(8)));
typedef float f32x4 __attribute__((ext_vector_type(4)));

__device__ __forceinline__ float bf2f(unsigned short u) {
    return __uint_as_float(((unsigned)u) << 16);
}
__device__ __forceinline__ unsigned short f2bf(float f) {
    unsigned u = __float_as_uint(f);
    unsigned r = u + 0x7fffu + ((u >> 16) & 1u);  // RNE
    return (unsigned short)(r >> 16);
}
__device__ __forceinline__ void unpack4(uint2 u, float& a, float& b, float& c, float& d) {
    a = __uint_as_float(u.x << 16);
    b = __uint_as_float(u.x & 0xffff0000u);
    c = __uint_as_float(u.y << 16);
    d = __uint_as_float(u.y & 0xffff0000u);
}
__device__ __forceinline__ uint2 pack4(float a, float b, float c, float d) {
    uint2 o;
    o.x = (unsigned)f2bf(a) | ((unsigned)f2bf(b) << 16);
    o.y = (unsigned)f2bf(c) | ((unsigned)f2bf(d) << 16);
    return o;
}

// ---------------- fused prep: cvt x -> bf16, transpose node_w, conv_w ----------------

__global__ void prep_kernel(const float* __restrict__ x, unsigned short* __restrict__ xbf, int nx4,
                            const float* __restrict__ nw, unsigned short* __restrict__ nwT,
                            const float* __restrict__ cw, unsigned short* __restrict__ cwT,
                            int b_cvt, int b_trn) {
    int b = blockIdx.x;
    if (b < b_cvt) {
        int i = (b * 256 + threadIdx.x) * 4;
        if (i < nx4 * 4) {
            float4 v = *reinterpret_cast<const float4*>(x + i);
            *reinterpret_cast<uint2*>(xbf + i) = pack4(v.x, v.y, v.z, v.w);
        }
    } else if (b < b_cvt + b_trn) {
        int idx = (b - b_cvt) * 256 + threadIdx.x;  // over 64*256
        int k = idx >> 8, n = idx & 255;
        nwT[n * 64 + k] = f2bf(nw[idx]);
    } else {
        int idx = (b - b_cvt - b_trn) * 256 + threadIdx.x;  // over 3*256*256
        int l = idx >> 16, rem = idx & 65535;
        int k = rem >> 8, n = rem & 255;
        cwT[(l << 16) + (n << 8) + k] = f2bf(cw[idx]);
    }
}

// ---------------- degree / CSR build ----------------

__global__ void deg_kernel(const int* __restrict__ col, int* __restrict__ cnt, int E) {
    int e = blockIdx.x * 256 + threadIdx.x;
    if (e < E) atomicAdd(&cnt[col[e]], 1);
}

__global__ void scan1_kernel(const int* __restrict__ cnt, int* __restrict__ scanbuf,
                             int* __restrict__ bsum, float* __restrict__ dis, int N) {
    __shared__ int s[512];
    int i = blockIdx.x * 512 + threadIdx.x;
    int c = (i < N) ? cnt[i] : 0;
    if (i < N) dis[i] = rsqrtf((float)c + 1.0f);  // +1 self-loop
    s[threadIdx.x] = c;
    __syncthreads();
    for (int off = 1; off < 512; off <<= 1) {
        int t = (threadIdx.x >= off) ? s[threadIdx.x - off] : 0;
        __syncthreads();
        s[threadIdx.x] += t;
        __syncthreads();
    }
    if (i < N) scanbuf[i] = s[threadIdx.x];
    if (threadIdx.x == 511) bsum[blockIdx.x] = s[511];
}

__global__ void scan2_kernel(const int* __restrict__ bsum, int* __restrict__ boff, int nb) {
    if (threadIdx.x == 0 && blockIdx.x == 0) {
        int acc = 0;
        for (int b = 0; b < nb; b++) { boff[b] = acc; acc += bsum[b]; }
    }
}

__global__ void scan3_kernel(const int* __restrict__ scanbuf, const int* __restrict__ boff,
                             int* __restrict__ rowstart, int N) {
    int i = blockIdx.x * 256 + threadIdx.x;
    if (i < N) rowstart[i + 1] = scanbuf[i] + boff[i >> 9];
    if (i == 0) rowstart[0] = 0;
}

__global__ void scatter_kernel(const int* __restrict__ row, const int* __restrict__ col,
                               const int* __restrict__ rowstart, int* __restrict__ fill,
                               int* __restrict__ eidx, int E) {
    int e = blockIdx.x * 256 + threadIdx.x;
    if (e < E) {
        int c = col[e];
        int pos = rowstart[c] + atomicAdd(&fill[c], 1);
        eidx[pos] = row[e];
    }
}

__global__ void zrow_kernel(unsigned short* __restrict__ p) {
    p[threadIdx.x] = 0;  // 256-wide zero row
}

// ---------------- GEMM: C[M,Nc] = A[M,K] * B[K,Nc], B given transposed (BT[Nc,K]) ----------------

__global__ __launch_bounds__(256)
void gemm_bt_kernel(const unsigned short* __restrict__ A, const unsigned short* __restrict__ BT,
                    unsigned short* __restrict__ C, const float* __restrict__ bias,
                    const float* __restrict__ scale, int M, int K, int Nc) {
    const int lane = threadIdx.x & 63;
    const int wave = threadIdx.x >> 6;
    const int wm = wave >> 1, wn = wave & 1;
    const int r = lane & 15, q = lane >> 4;
    const int m0 = blockIdx.x * 128 + wm * 64;
    const int n0 = blockIdx.y * 128 + wn * 64;

    f32x4 acc[4][4] = {};

    for (int k0 = 0; k0 < K; k0 += 32) {
        bf16x8 a[4], b[4];
#pragma unroll
        for (int i = 0; i < 4; i++) {
            int mr = m0 + i * 16 + r;
            if (mr >= M) mr = M - 1;  // clamp; masked at store
            a[i] = *reinterpret_cast<const bf16x8*>(A + (size_t)mr * K + k0 + q * 8);
        }
#pragma unroll
        for (int j = 0; j < 4; j++) {
            int nr = n0 + j * 16 + r;
            b[j] = *reinterpret_cast<const bf16x8*>(BT + (size_t)nr * K + k0 + q * 8);
        }
#pragma unroll
        for (int i = 0; i < 4; i++)
#pragma unroll
            for (int j = 0; j < 4; j++)
                acc[i][j] = __builtin_amdgcn_mfma_f32_16x16x32_bf16(a[i], b[j], acc[i][j], 0, 0, 0);
    }

#pragma unroll
    for (int i = 0; i < 4; i++) {
#pragma unroll
        for (int t = 0; t < 4; t++) {
            int mr = m0 + i * 16 + q * 4 + t;  // C/D: row = q*4+reg, col = lane&15
            if (mr < M) {
                float rs = scale ? scale[mr] : 1.0f;
#pragma unroll
                for (int j = 0; j < 4; j++) {
                    int nc = n0 + j * 16 + r;
                    float v = acc[i][j][t] * rs;
                    if (bias) v += bias[nc];
                    C[(size_t)mr * Nc + nc] = f2bf(v);
                }
            }
        }
    }
}

// ---------------- aggregation (GCN message passing) + fused BN stats ----------------
// hws[v] = dis[v] * (h @ W)[v] (pre-scaled in GEMM epilogue); hws[N] is a zero row.
// agg[v] = conv_b + dis[v] * ( hws[v] + sum_{e: col=v} hws[src] )
// HALF-WAVE PER NODE, no shfl: block 256 thr = 8 half-waves = 8 nodes.
// Lane l of a half-wave owns features l*8..l*8+7 (uint4 = 16 B; 32 lanes = full 512 B row).
// Edge indices are contiguous dwords -> 16 independent broadcast loads, then 16
// independent row gathers in flight. Padded slots gather the zero row.

__global__ __launch_bounds__(256)
void agg_kernel(const unsigned short* __restrict__ hws, const int* __restrict__ rowstart,
                const int* __restrict__ eidx, const float* __restrict__ dis,
                const float* __restrict__ cb, unsigned short* __restrict__ agg,
                float* __restrict__ stats, int N) {
    __shared__ float s_sum[8][256];
    __shared__ float s_sq[8][256];
    const int tid = threadIdx.x;
    const int hw_id = tid >> 5;
    const int l = tid & 31;
    const int fl = l * 8;
    const int v = blockIdx.x * 8 + hw_id;
    const bool valid = v < N;
    const int vc = valid ? v : N;

    // self row (zero row if invalid)
    float a[8];
    {
        uint4 sr = *reinterpret_cast<const uint4*>(hws + (size_t)vc * 256 + fl);
        unpack4(make_uint2(sr.x, sr.y), a[0], a[1], a[2], a[3]);
        unpack4(make_uint2(sr.z, sr.w), a[4], a[5], a[6], a[7]);
    }

    const int js = valid ? rowstart[v] : 0;
    const int je = valid ? rowstart[v + 1] : 0;
    const int deg = je - js;
    const float dv = valid ? dis[v] : 0.0f;

    for (int base = 0; base < deg; base += 16) {
        int id[16];
#pragma unroll
        for (int k = 0; k < 16; k++) {
            int raw = eidx[js + base + k];          // eidx has +64 pad; OOB value masked below
            id[k] = (base + k < deg) ? raw : N;     // N -> zero row
        }
        uint4 rr[16];
#pragma unroll
        for (int k = 0; k < 16; k++)
            rr[k] = *reinterpret_cast<const uint4*>(hws + (size_t)id[k] * 256 + fl);
#pragma unroll
        for (int k = 0; k < 16; k++) {
            float x0, x1, x2, x3;
            unpack4(make_uint2(rr[k].x, rr[k].y), x0, x1, x2, x3);
            a[0] += x0; a[1] += x1; a[2] += x2; a[3] += x3;
            unpack4(make_uint2(rr[k].z, rr[k].w), x0, x1, x2, x3);
            a[4] += x0; a[5] += x1; a[6] += x2; a[7] += x3;
        }
    }

    // finalize this node's 8 features per lane
    float4 cbl = *reinterpret_cast<const float4*>(cb + fl);
    float4 cbh = *reinterpret_cast<const float4*>(cb + fl + 4);
    float c8[8] = {cbl.x, cbl.y, cbl.z, cbl.w, cbh.x, cbh.y, cbh.z, cbh.w};
    float g[8];
#pragma unroll
    for (int j = 0; j < 8; j++) g[j] = valid ? (c8[j] + dv * a[j]) : 0.0f;

    if (valid) {
        uint2 lo = pack4(g[0], g[1], g[2], g[3]);
        uint2 hi = pack4(g[4], g[5], g[6], g[7]);
        *reinterpret_cast<uint4*>(agg + (size_t)v * 256 + fl) = make_uint4(lo.x, lo.y, hi.x, hi.y);
    }

#pragma unroll
    for (int j = 0; j < 8; j++) {
        s_sum[hw_id][fl + j] = g[j];
        s_sq[hw_id][fl + j] = g[j] * g[j];
    }
    __syncthreads();

    const int f = tid;
    float ts = 0.0f, tq = 0.0f;
#pragma unroll
    for (int w = 0; w < 8; w++) { ts += s_sum[w][f]; tq += s_sq[w][f]; }
    atomicAdd(&stats[f], ts);
    atomicAdd(&stats[256 + f], tq);
}

__global__ void bnfin_kernel(float* __restrict__ stats, const float* __restrict__ g,
                             const float* __restrict__ b, float* __restrict__ ss, int N) {
    int f = threadIdx.x;
    float inv_n = 1.0f / (float)N;
    float mean = stats[f] * inv_n;
    float var = stats[256 + f] * inv_n - mean * mean;
    float rstd = rsqrtf(var + 1e-5f);
    float sc = g[f] * rstd;
    ss[f] = sc;
    ss[256 + f] = b[f] - mean * sc;
    stats[f] = 0.0f;          // clear for next layer
    stats[256 + f] = 0.0f;
}

__global__ void elem_kernel(const unsigned short* __restrict__ agg, const float* __restrict__ ss,
                            unsigned short* __restrict__ h, size_t total) {
    size_t i = ((size_t)blockIdx.x * 256 + threadIdx.x) * 4;
    if (i < total) {
        float a0, a1, a2, a3;
        unpack4(*reinterpret_cast<const uint2*>(agg + i), a0, a1, a2, a3);
        int f = (int)(i & 255);
        float r0 = fmaxf(a0 * ss[f] + ss[256 + f], 0.0f);
        float r1 = fmaxf(a1 * ss[f + 1] + ss[256 + f + 1], 0.0f);
        float r2 = fmaxf(a2 * ss[f + 2] + ss[256 + f + 2], 0.0f);
        float r3 = fmaxf(a3 * ss[f + 3] + ss[256 + f + 3], 0.0f);
        *reinterpret_cast<uint2*>(h + i) = pack4(r0, r1, r2, r3);
    }
}

// ---------------- global_add_pool (batch is sorted) ----------------

__global__ __launch_bounds__(256)
void pool_kernel(const unsigned short* __restrict__ h, const int* __restrict__ batch,
                 float* __restrict__ g, int N) {
    __shared__ int sb[256];
    int f = threadIdx.x;
    int r0 = blockIdx.x * 256;
    int rows = min(256, N - r0);
    sb[f] = (r0 + f < N) ? batch[r0 + f] : -1;
    __syncthreads();
    float acc = 0.0f;
    int cur = sb[0];
    for (int t = 0; t < rows; t++) {
        int b = sb[t];
        if (b != cur) {
            atomicAdd(&g[cur * 256 + f], acc);
            acc = 0.0f;
            cur = b;
        }
        acc += bf2f(h[(size_t)(r0 + t) * 256 + f]);
    }
    atomicAdd(&g[cur * 256 + f], acc);
}

// ---------------- head MLP: relu(g@w1+b1)@w2+b2 ----------------

__global__ void head_kernel(const float* __restrict__ g, const float* __restrict__ w1,
                            const float* __restrict__ b1, const float* __restrict__ w2,
                            const float* __restrict__ b2, float* __restrict__ out) {
    __shared__ float gr[256];
    __shared__ float z[128];
    int b = blockIdx.x, t = threadIdx.x;
    gr[t] = g[b * 256 + t];
    gr[t + 128] = g[b * 256 + 128 + t];
    __syncthreads();
    float acc = b1[t];
    for (int k = 0; k < 256; k++) acc += gr[k] * w1[k * 128 + t];
    z[t] = fmaxf(acc, 0.0f);
    __syncthreads();
    if (t < 12) {
        float o = b2[t];
        for (int k = 0; k < 128; k++) o += z[k] * w2[k * 12 + t];
        out[b * 12 + t] = o;
    }
}

// ---------------- launch ----------------

extern "C" void kernel_launch(void* const* d_in, const int* in_sizes, int n_in,
                              void* d_out, int out_size, void* d_ws, size_t ws_size,
                              hipStream_t stream) {
    const float* x      = (const float*)d_in[0];
    const int*   ei     = (const int*)d_in[1];
    const int*   batch  = (const int*)d_in[2];
    const float* node_w = (const float*)d_in[3];
    const float* node_b = (const float*)d_in[4];
    const float* conv_w = (const float*)d_in[5];
    const float* conv_b = (const float*)d_in[6];
    const float* bn_g   = (const float*)d_in[7];
    const float* bn_b   = (const float*)d_in[8];
    const float* hw1    = (const float*)d_in[9];
    const float* hb1    = (const float*)d_in[10];
    const float* hw2    = (const float*)d_in[11];
    const float* hb2    = (const float*)d_in[12];
    float* out = (float*)d_out;

    const int N = in_sizes[2];
    const int E = in_sizes[1] / 2;
    const int IN = 64, H = 256, L = 3;

    char* base = (char*)d_ws;
    size_t off = 0;
    auto alloc = [&](size_t bytes) -> void* {
        off = (off + 255) & ~(size_t)255;
        void* p = base + off;
        off += bytes;
        return p;
    };
    unsigned short* xbf = (unsigned short*)alloc((size_t)N * IN * 2);
    unsigned short* h   = (unsigned short*)alloc((size_t)N * H * 2);
    unsigned short* hws = (unsigned short*)alloc((size_t)(N + 1) * H * 2);  // +1 zero row
    unsigned short* agg = (unsigned short*)alloc((size_t)N * H * 2);
    unsigned short* nwT = (unsigned short*)alloc((size_t)IN * H * 2);
    unsigned short* cwT = (unsigned short*)alloc((size_t)L * H * H * 2);
    int* cnt      = (int*)alloc((size_t)N * 4);
    int* fill     = (int*)alloc((size_t)N * 4);
    int* rowstart = (int*)alloc((size_t)(N + 1) * 4);
    int* scanbuf  = (int*)alloc((size_t)N * 4);
    int* bsum     = (int*)alloc(1024);
    int* boff     = (int*)alloc(1024);
    int* eidx     = (int*)alloc((size_t)(E + 64) * 4);  // +64 pad (OOB reads masked)
    float* dis    = (float*)alloc((size_t)N * 4);
    float* stats  = (float*)alloc(512 * 4);
    float* ss     = (float*)alloc(512 * 4);
    float* gpool  = (float*)alloc(64 * H * 4);

    const int* row = ei;
    const int* col = ei + E;

    hipMemsetAsync(cnt, 0, (size_t)N * 4, stream);
    hipMemsetAsync(fill, 0, (size_t)N * 4, stream);
    hipMemsetAsync(stats, 0, 512 * 4, stream);
    zrow_kernel<<<dim3(1), 256, 0, stream>>>(hws + (size_t)N * H);

    int b_cvt = (N * IN / 4 + 255) / 256;
    int b_trn = (IN * H) / 256;
    int b_trc = (L * H * H) / 256;
    prep_kernel<<<dim3(b_cvt + b_trn + b_trc), 256, 0, stream>>>(
        x, xbf, N * IN / 4, node_w, nwT, conv_w, cwT, b_cvt, b_trn);

    deg_kernel<<<dim3((E + 255) / 256), 256, 0, stream>>>(col, cnt, E);
    int nb = (N + 511) / 512;
    scan1_kernel<<<dim3(nb), 512, 0, stream>>>(cnt, scanbuf, bsum, dis, N);
    scan2_kernel<<<dim3(1), 64, 0, stream>>>(bsum, boff, nb);
    scan3_kernel<<<dim3((N + 255) / 256), 256, 0, stream>>>(scanbuf, boff, rowstart, N);
    scatter_kernel<<<dim3((E + 255) / 256), 256, 0, stream>>>(row, col, rowstart, fill, eidx, E);

    dim3 gg((N + 127) / 128, H / 128);
    gemm_bt_kernel<<<gg, 256, 0, stream>>>(xbf, nwT, h, node_b, nullptr, N, IN, H);

    for (int l = 0; l < L; l++) {
        // hws = dis[v] * (h @ conv_w[l])  (scale fused into epilogue)
        gemm_bt_kernel<<<gg, 256, 0, stream>>>(h, cwT + (size_t)l * H * H, hws, nullptr, dis, N, H, H);
        agg_kernel<<<dim3((N + 7) / 8), 256, 0, stream>>>(hws, rowstart, eidx, dis,
                                                          conv_b + l * H, agg, stats, N);
        bnfin_kernel<<<dim3(1), 256, 0, stream>>>(stats, bn_g + l * H, bn_b + l * H, ss, N);
        size_t total = (size_t)N * H;
        elem_kernel<<<dim3((int)((total / 4 + 255) / 256)), 256, 0, stream>>>(agg, ss, h, total);
    }

    hipMemsetAsync(gpool, 0, 64 * H * 4, stream);
    pool_kernel<<<dim3((N + 255) / 256), 256, 0, stream>>>(h, batch, gpool, N);
    head_kernel<<<dim3(64), 128, 0, stream>>>(gpool, hw1, hb1, hw2, hb2, out);
}

// Round 7
// 649.188 us; speedup vs baseline: 4.5794x; 1.4059x over previous
//
#include <hip/hip_runtime.h>
#include <stdint.h>

#define AS1 __attribute__((address_space(1)))
#define AS3 __attribute__((address_space(3)))

typedef __bf16 bf16x8 __attribute__((ext_vector_type(8)));
typedef float f32x4 __attribute__((ext_vector_type(4)));

__device__ __forceinline__ float bf2f(unsigned short u) {
    return __uint_as_float(((unsigned)u) << 16);
}
__device__ __forceinline__ unsigned short f2bf(float f) {
    unsigned u = __float_as_uint(f);
    unsigned r = u + 0x7fffu + ((u >> 16) & 1u);  // RNE
    return (unsigned short)(r >> 16);
}
__device__ __forceinline__ void unpack4(uint2 u, float& a, float& b, float& c, float& d) {
    a = __uint_as_float(u.x << 16);
    b = __uint_as_float(u.x & 0xffff0000u);
    c = __uint_as_float(u.y << 16);
    d = __uint_as_float(u.y & 0xffff0000u);
}
__device__ __forceinline__ uint2 pack4(float a, float b, float c, float d) {
    uint2 o;
    o.x = (unsigned)f2bf(a) | ((unsigned)f2bf(b) << 16);
    o.y = (unsigned)f2bf(c) | ((unsigned)f2bf(d) << 16);
    return o;
}

// ---------------- fused prep: cvt x -> bf16, transpose node_w, conv_w ----------------

__global__ void prep_kernel(const float* __restrict__ x, unsigned short* __restrict__ xbf, int nx4,
                            const float* __restrict__ nw, unsigned short* __restrict__ nwT,
                            const float* __restrict__ cw, unsigned short* __restrict__ cwT,
                            int b_cvt, int b_trn) {
    int b = blockIdx.x;
    if (b < b_cvt) {
        int i = (b * 256 + threadIdx.x) * 4;
        if (i < nx4 * 4) {
            float4 v = *reinterpret_cast<const float4*>(x + i);
            *reinterpret_cast<uint2*>(xbf + i) = pack4(v.x, v.y, v.z, v.w);
        }
    } else if (b < b_cvt + b_trn) {
        int idx = (b - b_cvt) * 256 + threadIdx.x;  // over 64*256
        int k = idx >> 8, n = idx & 255;
        nwT[n * 64 + k] = f2bf(nw[idx]);
    } else {
        int idx = (b - b_cvt - b_trn) * 256 + threadIdx.x;  // over 3*256*256
        int l = idx >> 16, rem = idx & 65535;
        int k = rem >> 8, n = rem & 255;
        cwT[(l << 16) + (n << 8) + k] = f2bf(cw[idx]);
    }
}

// ---------------- degree / CSR build ----------------

__global__ void deg_kernel(const int* __restrict__ col, int* __restrict__ cnt, int E) {
    int e = blockIdx.x * 256 + threadIdx.x;
    if (e < E) atomicAdd(&cnt[col[e]], 1);
}

__global__ void scan1_kernel(const int* __restrict__ cnt, int* __restrict__ scanbuf,
                             int* __restrict__ bsum, float* __restrict__ dis, int N) {
    __shared__ int s[512];
    int i = blockIdx.x * 512 + threadIdx.x;
    int c = (i < N) ? cnt[i] : 0;
    if (i < N) dis[i] = rsqrtf((float)c + 1.0f);  // +1 self-loop
    s[threadIdx.x] = c;
    __syncthreads();
    for (int off = 1; off < 512; off <<= 1) {
        int t = (threadIdx.x >= off) ? s[threadIdx.x - off] : 0;
        __syncthreads();
        s[threadIdx.x] += t;
        __syncthreads();
    }
    if (i < N) scanbuf[i] = s[threadIdx.x];
    if (threadIdx.x == 511) bsum[blockIdx.x] = s[511];
}

__global__ void scan2_kernel(const int* __restrict__ bsum, int* __restrict__ boff, int nb) {
    if (threadIdx.x == 0 && blockIdx.x == 0) {
        int acc = 0;
        for (int b = 0; b < nb; b++) { boff[b] = acc; acc += bsum[b]; }
    }
}

__global__ void scan3_kernel(const int* __restrict__ scanbuf, const int* __restrict__ boff,
                             int* __restrict__ rowstart, int N) {
    int i = blockIdx.x * 256 + threadIdx.x;
    if (i < N) rowstart[i + 1] = scanbuf[i] + boff[i >> 9];
    if (i == 0) rowstart[0] = 0;
}

__global__ void scatter_kernel(const int* __restrict__ row, const int* __restrict__ col,
                               const int* __restrict__ rowstart, int* __restrict__ fill,
                               int* __restrict__ eidx, int E) {
    int e = blockIdx.x * 256 + threadIdx.x;
    if (e < E) {
        int c = col[e];
        int pos = rowstart[c] + atomicAdd(&fill[c], 1);
        eidx[pos] = row[e];
    }
}

__global__ void zrow_kernel(unsigned short* __restrict__ p) {
    p[threadIdx.x] = 0;  // 256-wide zero row
}

// ---------------- GEMM (m97 recipe): C[M,Nc] = A[M,K] * BT[Nc,K]^T ----------------
// bf16 in, fp32 MFMA accumulate, bf16 out, optional bias[nc] / per-row scale[mr].
// Block 256 thr = 4 waves (2x2), tile 128x128, BK=32, LDS staged via
// global_load_lds width=16 (wave-uniform LDS base + lane*16; [row][32k] layout).

__global__ __launch_bounds__(256)
void gemm_bt_kernel(const unsigned short* __restrict__ A, const unsigned short* __restrict__ BT,
                    unsigned short* __restrict__ C, const float* __restrict__ bias,
                    const float* __restrict__ scale, int M, int K, int Nc) {
    __shared__ unsigned short As[128 * 32];
    __shared__ unsigned short Bs[128 * 32];

    const int lane = threadIdx.x & 63;
    const int wave = threadIdx.x >> 6;
    const int wm = wave >> 1, wn = wave & 1;
    const int r = lane & 15, q = lane >> 4;
    const int m0b = blockIdx.x * 128;
    const int n0b = blockIdx.y * 128;
    const int m0 = m0b + wm * 64;
    const int n0 = n0b + wn * 64;

    f32x4 acc[4][4] = {};

    for (int k0 = 0; k0 < K; k0 += 32) {
        __syncthreads();  // previous tile consumed
#pragma unroll
        for (int j = 0; j < 2; j++) {
            int s = threadIdx.x + j * 256;        // 512 slots of 16 B
            int row = s >> 2, kp = s & 3;
            int mr = m0b + row;
            if (mr >= M) mr = M - 1;
            const unsigned short* ga = A + (size_t)mr * K + k0 + kp * 8;
            __builtin_amdgcn_global_load_lds((const AS1 void*)ga, (AS3 void*)(As + s * 8), 16, 0, 0);
            int nr = n0b + row;                    // Nc is a multiple of 128
            const unsigned short* gb = BT + (size_t)nr * K + k0 + kp * 8;
            __builtin_amdgcn_global_load_lds((const AS1 void*)gb, (AS3 void*)(Bs + s * 8), 16, 0, 0);
        }
        __syncthreads();  // drains vmcnt -> LDS ready

        bf16x8 a[4], b[4];
#pragma unroll
        for (int i = 0; i < 4; i++)
            a[i] = *reinterpret_cast<const bf16x8*>(As + ((wm * 64 + i * 16 + r) * 32 + q * 8));
#pragma unroll
        for (int j = 0; j < 4; j++)
            b[j] = *reinterpret_cast<const bf16x8*>(Bs + ((wn * 64 + j * 16 + r) * 32 + q * 8));
#pragma unroll
        for (int i = 0; i < 4; i++)
#pragma unroll
            for (int j = 0; j < 4; j++)
                acc[i][j] = __builtin_amdgcn_mfma_f32_16x16x32_bf16(a[i], b[j], acc[i][j], 0, 0, 0);
    }

#pragma unroll
    for (int i = 0; i < 4; i++) {
#pragma unroll
        for (int t = 0; t < 4; t++) {
            int mr = m0 + i * 16 + q * 4 + t;  // C/D: row = q*4+reg, col = lane&15
            if (mr < M) {
                float rs = scale ? scale[mr] : 1.0f;
#pragma unroll
                for (int j = 0; j < 4; j++) {
                    int nc = n0 + j * 16 + r;
                    float v = acc[i][j][t] * rs;
                    if (bias) v += bias[nc];
                    C[(size_t)mr * Nc + nc] = f2bf(v);
                }
            }
        }
    }
}

// ---------------- aggregation (R4 ping-pong, measured-best) + fused BN stats ----------------
// hws[v] = dis[v] * (h @ W)[v]; hws[N] is a zero row.
// agg[v] = conv_b + dis[v] * ( hws[v] + sum_{e: col=v} hws[src] )
// Wave handles 4 nodes. Half-wave layout: lane&31 owns 8 features (uint4 = 16 B),
// lane>>5 picks edge parity -> each wave-wide load covers 2 edges (1 KB).
// Metadata prefetched up front; gathers ping-pong between two 8-deep uint4 buffers
// across nodes so ~8 KB stays in flight with no full vmcnt drains on the common path.

__global__ __launch_bounds__(256)
void agg_kernel(const unsigned short* __restrict__ hws, const int* __restrict__ rowstart,
                const int* __restrict__ eidx, const float* __restrict__ dis,
                const float* __restrict__ cb, unsigned short* __restrict__ agg,
                float* __restrict__ stats, int N) {
    __shared__ float s_sum[4][256];
    __shared__ float s_sq[4][256];
    const int lane = threadIdx.x & 63;
    const int wave = threadIdx.x >> 6;
    const int sub = lane >> 5;         // edge parity
    const int fl = (lane & 31) * 8;    // feature base (8 features per lane)

    const int vb = __builtin_amdgcn_readfirstlane(blockIdx.x * 16 + wave * 4);

    // scalar metadata (wave-uniform)
    int rs[5];
#pragma unroll
    for (int s = 0; s < 5; s++) rs[s] = rowstart[min(vb + s, N)];
    int js[4], de[4];
    float dvv[4];
#pragma unroll
    for (int s = 0; s < 4; s++) {
        js[s] = rs[s];
        de[s] = (vb + s < N) ? (rs[s + 1] - rs[s]) : 0;
        dvv[s] = (vb + s < N) ? dis[vb + s] : 0.0f;
    }

    // vector prefetch: first 64-chunk of edge indices per node, self rows
    int idx0 = (lane < de[0]) ? eidx[js[0] + lane] : N;
    int idx1 = (lane < de[1]) ? eidx[js[1] + lane] : N;
    int idx2 = (lane < de[2]) ? eidx[js[2] + lane] : N;
    int idx3 = (lane < de[3]) ? eidx[js[3] + lane] : N;
    uint4 sf[4];
#pragma unroll
    for (int s = 0; s < 4; s++)
        sf[s] = *reinterpret_cast<const uint4*>(hws + (size_t)min(vb + s, N) * 256 + fl);

    // per-lane bias slice
    float4 cbl = *reinterpret_cast<const float4*>(cb + fl);
    float4 cbh = *reinterpret_cast<const float4*>(cb + fl + 4);
    float c8[8] = {cbl.x, cbl.y, cbl.z, cbl.w, cbh.x, cbh.y, cbh.z, cbh.w};

    float ps[8] = {}, pq[8] = {};

    uint4 rA[8], rB[8];

    auto issue = [&](int myidx, uint4 (&rr)[8]) {
#pragma unroll
        for (int k = 0; k < 8; k++) {
            int u = __shfl(myidx, 2 * k + sub);
            rr[k] = *reinterpret_cast<const uint4*>(hws + (size_t)u * 256 + fl);
        }
    };

    auto consume = [&](int s, int js_s, int d, float dvs, int myidx, uint4 (&rr)[8]) {
        float a[8] = {};
#pragma unroll
        for (int k = 0; k < 8; k++) {
            float x0, x1, x2, x3;
            unpack4(make_uint2(rr[k].x, rr[k].y), x0, x1, x2, x3);
            a[0] += x0; a[1] += x1; a[2] += x2; a[3] += x3;
            unpack4(make_uint2(rr[k].z, rr[k].w), x0, x1, x2, x3);
            a[4] += x0; a[5] += x1; a[6] += x2; a[7] += x3;
        }
        // rest of first chunk (deg > 16), same buffer (rare)
        int cnp = min(64, (d + 15) & ~15);
        for (int t = 16; t < cnp; t += 16) {
#pragma unroll
            for (int k = 0; k < 8; k++) {
                int u = __shfl(myidx, t + 2 * k + sub);
                rr[k] = *reinterpret_cast<const uint4*>(hws + (size_t)u * 256 + fl);
            }
#pragma unroll
            for (int k = 0; k < 8; k++) {
                float x0, x1, x2, x3;
                unpack4(make_uint2(rr[k].x, rr[k].y), x0, x1, x2, x3);
                a[0] += x0; a[1] += x1; a[2] += x2; a[3] += x3;
                unpack4(make_uint2(rr[k].z, rr[k].w), x0, x1, x2, x3);
                a[4] += x0; a[5] += x1; a[6] += x2; a[7] += x3;
            }
        }
        // chunks beyond 64 edges (very rare)
        for (int base = 64; base < d; base += 64) {
            int mi = (base + lane < d) ? eidx[js_s + base + lane] : N;
            int cn2 = min(64, d - base);
            int cnp2 = (cn2 + 15) & ~15;
            for (int t = 0; t < cnp2; t += 16) {
#pragma unroll
                for (int k = 0; k < 8; k++) {
                    int u = __shfl(mi, t + 2 * k + sub);
                    rr[k] = *reinterpret_cast<const uint4*>(hws + (size_t)u * 256 + fl);
                }
#pragma unroll
                for (int k = 0; k < 8; k++) {
                    float x0, x1, x2, x3;
                    unpack4(make_uint2(rr[k].x, rr[k].y), x0, x1, x2, x3);
                    a[0] += x0; a[1] += x1; a[2] += x2; a[3] += x3;
                    unpack4(make_uint2(rr[k].z, rr[k].w), x0, x1, x2, x3);
                    a[4] += x0; a[5] += x1; a[6] += x2; a[7] += x3;
                }
            }
        }
        // combine halves (edge parity)
#pragma unroll
        for (int j = 0; j < 8; j++) a[j] += __shfl_xor(a[j], 32);
        // self + bias + scale
        float x0, x1, x2, x3;
        unpack4(make_uint2(sf[s].x, sf[s].y), x0, x1, x2, x3);
        a[0] += x0; a[1] += x1; a[2] += x2; a[3] += x3;
        unpack4(make_uint2(sf[s].z, sf[s].w), x0, x1, x2, x3);
        a[4] += x0; a[5] += x1; a[6] += x2; a[7] += x3;
        float g[8];
#pragma unroll
        for (int j = 0; j < 8; j++) g[j] = c8[j] + dvs * a[j];
        if (vb + s < N && sub == 0) {
            uint2 lo = pack4(g[0], g[1], g[2], g[3]);
            uint2 hi = pack4(g[4], g[5], g[6], g[7]);
            *reinterpret_cast<uint4*>(agg + (size_t)(vb + s) * 256 + fl) =
                make_uint4(lo.x, lo.y, hi.x, hi.y);
#pragma unroll
            for (int j = 0; j < 8; j++) { ps[j] += g[j]; pq[j] += g[j] * g[j]; }
        }
    };

    issue(idx0, rA);
    issue(idx1, rB);
    consume(0, js[0], de[0], dvv[0], idx0, rA);
    issue(idx2, rA);
    consume(1, js[1], de[1], dvv[1], idx1, rB);
    issue(idx3, rB);
    consume(2, js[2], de[2], dvv[2], idx2, rA);
    consume(3, js[3], de[3], dvv[3], idx3, rB);

    if (sub == 0) {
#pragma unroll
        for (int j = 0; j < 8; j++) {
            s_sum[wave][fl + j] = ps[j];
            s_sq[wave][fl + j] = pq[j];
        }
    }
    __syncthreads();

    int f = threadIdx.x;
    float ts = s_sum[0][f] + s_sum[1][f] + s_sum[2][f] + s_sum[3][f];
    float tq = s_sq[0][f] + s_sq[1][f] + s_sq[2][f] + s_sq[3][f];
    atomicAdd(&stats[f], ts);
    atomicAdd(&stats[256 + f], tq);
}

__global__ void bnfin_kernel(float* __restrict__ stats, const float* __restrict__ g,
                             const float* __restrict__ b, float* __restrict__ ss, int N) {
    int f = threadIdx.x;
    float inv_n = 1.0f / (float)N;
    float mean = stats[f] * inv_n;
    float var = stats[256 + f] * inv_n - mean * mean;
    float rstd = rsqrtf(var + 1e-5f);
    float sc = g[f] * rstd;
    ss[f] = sc;
    ss[256 + f] = b[f] - mean * sc;
    stats[f] = 0.0f;          // clear for next layer
    stats[256 + f] = 0.0f;
}

__global__ void elem_kernel(const unsigned short* __restrict__ agg, const float* __restrict__ ss,
                            unsigned short* __restrict__ h, size_t total) {
    size_t i = ((size_t)blockIdx.x * 256 + threadIdx.x) * 4;
    if (i < total) {
        float a0, a1, a2, a3;
        unpack4(*reinterpret_cast<const uint2*>(agg + i), a0, a1, a2, a3);
        int f = (int)(i & 255);
        float r0 = fmaxf(a0 * ss[f] + ss[256 + f], 0.0f);
        float r1 = fmaxf(a1 * ss[f + 1] + ss[256 + f + 1], 0.0f);
        float r2 = fmaxf(a2 * ss[f + 2] + ss[256 + f + 2], 0.0f);
        float r3 = fmaxf(a3 * ss[f + 3] + ss[256 + f + 3], 0.0f);
        *reinterpret_cast<uint2*>(h + i) = pack4(r0, r1, r2, r3);
    }
}

// ---------------- global_add_pool (batch is sorted) ----------------

__global__ __launch_bounds__(256)
void pool_kernel(const unsigned short* __restrict__ h, const int* __restrict__ batch,
                 float* __restrict__ g, int N) {
    __shared__ int sb[256];
    int f = threadIdx.x;
    int r0 = blockIdx.x * 256;
    int rows = min(256, N - r0);
    sb[f] = (r0 + f < N) ? batch[r0 + f] : -1;
    __syncthreads();
    float acc = 0.0f;
    int cur = sb[0];
    for (int t = 0; t < rows; t++) {
        int b = sb[t];
        if (b != cur) {
            atomicAdd(&g[cur * 256 + f], acc);
            acc = 0.0f;
            cur = b;
        }
        acc += bf2f(h[(size_t)(r0 + t) * 256 + f]);
    }
    atomicAdd(&g[cur * 256 + f], acc);
}

// ---------------- head MLP: relu(g@w1+b1)@w2+b2 ----------------

__global__ void head_kernel(const float* __restrict__ g, const float* __restrict__ w1,
                            const float* __restrict__ b1, const float* __restrict__ w2,
                            const float* __restrict__ b2, float* __restrict__ out) {
    __shared__ float gr[256];
    __shared__ float z[128];
    int b = blockIdx.x, t = threadIdx.x;
    gr[t] = g[b * 256 + t];
    gr[t + 128] = g[b * 256 + 128 + t];
    __syncthreads();
    float acc = b1[t];
    for (int k = 0; k < 256; k++) acc += gr[k] * w1[k * 128 + t];
    z[t] = fmaxf(acc, 0.0f);
    __syncthreads();
    if (t < 12) {
        float o = b2[t];
        for (int k = 0; k < 128; k++) o += z[k] * w2[k * 12 + t];
        out[b * 12 + t] = o;
    }
}

// ---------------- launch ----------------

extern "C" void kernel_launch(void* const* d_in, const int* in_sizes, int n_in,
                              void* d_out, int out_size, void* d_ws, size_t ws_size,
                              hipStream_t stream) {
    const float* x      = (const float*)d_in[0];
    const int*   ei     = (const int*)d_in[1];
    const int*   batch  = (const int*)d_in[2];
    const float* node_w = (const float*)d_in[3];
    const float* node_b = (const float*)d_in[4];
    const float* conv_w = (const float*)d_in[5];
    const float* conv_b = (const float*)d_in[6];
    const float* bn_g   = (const float*)d_in[7];
    const float* bn_b   = (const float*)d_in[8];
    const float* hw1    = (const float*)d_in[9];
    const float* hb1    = (const float*)d_in[10];
    const float* hw2    = (const float*)d_in[11];
    const float* hb2    = (const float*)d_in[12];
    float* out = (float*)d_out;

    const int N = in_sizes[2];
    const int E = in_sizes[1] / 2;
    const int IN = 64, H = 256, L = 3;

    char* base = (char*)d_ws;
    size_t off = 0;
    auto alloc = [&](size_t bytes) -> void* {
        off = (off + 255) & ~(size_t)255;
        void* p = base + off;
        off += bytes;
        return p;
    };
    unsigned short* xbf = (unsigned short*)alloc((size_t)N * IN * 2);
    unsigned short* h   = (unsigned short*)alloc((size_t)N * H * 2);
    unsigned short* hws = (unsigned short*)alloc((size_t)(N + 1) * H * 2);  // +1 zero row
    unsigned short* agg = (unsigned short*)alloc((size_t)N * H * 2);
    unsigned short* nwT = (unsigned short*)alloc((size_t)IN * H * 2);
    unsigned short* cwT = (unsigned short*)alloc((size_t)L * H * H * 2);
    int* cnt      = (int*)alloc((size_t)N * 4);
    int* fill     = (int*)alloc((size_t)N * 4);
    int* rowstart = (int*)alloc((size_t)(N + 1) * 4);
    int* scanbuf  = (int*)alloc((size_t)N * 4);
    int* bsum     = (int*)alloc(1024);
    int* boff     = (int*)alloc(1024);
    int* eidx     = (int*)alloc((size_t)(E + 64) * 4);  // +64 pad
    float* dis    = (float*)alloc((size_t)N * 4);
    float* stats  = (float*)alloc(512 * 4);
    float* ss     = (float*)alloc(512 * 4);
    float* gpool  = (float*)alloc(64 * H * 4);

    const int* row = ei;
    const int* col = ei + E;

    hipMemsetAsync(cnt, 0, (size_t)N * 4, stream);
    hipMemsetAsync(fill, 0, (size_t)N * 4, stream);
    hipMemsetAsync(stats, 0, 512 * 4, stream);
    zrow_kernel<<<dim3(1), 256, 0, stream>>>(hws + (size_t)N * H);

    int b_cvt = (N * IN / 4 + 255) / 256;
    int b_trn = (IN * H) / 256;
    int b_trc = (L * H * H) / 256;
    prep_kernel<<<dim3(b_cvt + b_trn + b_trc), 256, 0, stream>>>(
        x, xbf, N * IN / 4, node_w, nwT, conv_w, cwT, b_cvt, b_trn);

    deg_kernel<<<dim3((E + 255) / 256), 256, 0, stream>>>(col, cnt, E);
    int nb = (N + 511) / 512;
    scan1_kernel<<<dim3(nb), 512, 0, stream>>>(cnt, scanbuf, bsum, dis, N);
    scan2_kernel<<<dim3(1), 64, 0, stream>>>(bsum, boff, nb);
    scan3_kernel<<<dim3((N + 255) / 256), 256, 0, stream>>>(scanbuf, boff, rowstart, N);
    scatter_kernel<<<dim3((E + 255) / 256), 256, 0, stream>>>(row, col, rowstart, fill, eidx, E);

    dim3 gg((N + 127) / 128, H / 128);
    gemm_bt_kernel<<<gg, 256, 0, stream>>>(xbf, nwT, h, node_b, nullptr, N, IN, H);

    for (int l = 0; l < L; l++) {
        // hws = dis[v] * (h @ conv_w[l])  (scale fused into epilogue)
        gemm_bt_kernel<<<gg, 256, 0, stream>>>(h, cwT + (size_t)l * H * H, hws, nullptr, dis, N, H, H);
        agg_kernel<<<dim3((N + 15) / 16), 256, 0, stream>>>(hws, rowstart, eidx, dis,
                                                            conv_b + l * H, agg, stats, N);
        bnfin_kernel<<<dim3(1), 256, 0, stream>>>(stats, bn_g + l * H, bn_b + l * H, ss, N);
        size_t total = (size_t)N * H;
        elem_kernel<<<dim3((int)((total / 4 + 255) / 256)), 256, 0, stream>>>(agg, ss, h, total);
    }

    hipMemsetAsync(gpool, 0, 64 * H * 4, stream);
    pool_kernel<<<dim3((N + 255) / 256), 256, 0, stream>>>(h, batch, gpool, N);
    head_kernel<<<dim3(64), 128, 0, stream>>>(gpool, hw1, hb1, hw2, hb2, out);
}

// Round 8
// 643.739 us; speedup vs baseline: 4.6181x; 1.0085x over previous
//
#include <hip/hip_runtime.h>
#include <stdint.h>

#define AS1 __attribute__((address_space(1)))
#define AS3 __attribute__((address_space(3)))

typedef __bf16 bf16x8 __attribute__((ext_vector_type(8)));
typedef float f32x4 __attribute__((ext_vector_type(4)));

__device__ __forceinline__ float bf2f(unsigned short u) {
    return __uint_as_float(((unsigned)u) << 16);
}
__device__ __forceinline__ unsigned short f2bf(float f) {
    unsigned u = __float_as_uint(f);
    unsigned r = u + 0x7fffu + ((u >> 16) & 1u);  // RNE
    return (unsigned short)(r >> 16);
}
__device__ __forceinline__ void unpack4(uint2 u, float& a, float& b, float& c, float& d) {
    a = __uint_as_float(u.x << 16);
    b = __uint_as_float(u.x & 0xffff0000u);
    c = __uint_as_float(u.y << 16);
    d = __uint_as_float(u.y & 0xffff0000u);
}
__device__ __forceinline__ uint2 pack4(float a, float b, float c, float d) {
    uint2 o;
    o.x = (unsigned)f2bf(a) | ((unsigned)f2bf(b) << 16);
    o.y = (unsigned)f2bf(c) | ((unsigned)f2bf(d) << 16);
    return o;
}

// ---------------- prep: transpose conv_w (layers 1,2 used; 0 harmlessly included) ----------------

__global__ void prep_kernel(const float* __restrict__ cw, unsigned short* __restrict__ cwT) {
    int idx = blockIdx.x * 256 + threadIdx.x;  // over 3*256*256
    int l = idx >> 16, rem = idx & 65535;
    int k = rem >> 8, n = rem & 255;
    cwT[(l << 16) + (n << 8) + k] = f2bf(cw[idx]);
}

// ---------------- degree / CSR build ----------------

__global__ void deg_kernel(const int* __restrict__ col, int* __restrict__ cnt, int E) {
    int e = blockIdx.x * 256 + threadIdx.x;
    if (e < E) atomicAdd(&cnt[col[e]], 1);
}

__global__ void scan1_kernel(const int* __restrict__ cnt, int* __restrict__ scanbuf,
                             int* __restrict__ bsum, float* __restrict__ dis, int N) {
    __shared__ int s[512];
    int i = blockIdx.x * 512 + threadIdx.x;
    int c = (i < N) ? cnt[i] : 0;
    if (i < N) dis[i] = rsqrtf((float)c + 1.0f);  // +1 self-loop
    s[threadIdx.x] = c;
    __syncthreads();
    for (int off = 1; off < 512; off <<= 1) {
        int t = (threadIdx.x >= off) ? s[threadIdx.x - off] : 0;
        __syncthreads();
        s[threadIdx.x] += t;
        __syncthreads();
    }
    if (i < N) scanbuf[i] = s[threadIdx.x];
    if (threadIdx.x == 511) bsum[blockIdx.x] = s[511];
}

__global__ void scan2_kernel(const int* __restrict__ bsum, int* __restrict__ boff, int nb) {
    if (threadIdx.x == 0 && blockIdx.x == 0) {
        int acc = 0;
        for (int b = 0; b < nb; b++) { boff[b] = acc; acc += bsum[b]; }
    }
}

__global__ void scan3_kernel(const int* __restrict__ scanbuf, const int* __restrict__ boff,
                             int* __restrict__ rowstart, int N) {
    int i = blockIdx.x * 256 + threadIdx.x;
    if (i < N) rowstart[i + 1] = scanbuf[i] + boff[i >> 9];
    if (i == 0) rowstart[0] = 0;
}

// scatter edges into CSR; also accumulate sdis[v] = sum of dis[src] over in-edges
__global__ void scatter_kernel(const int* __restrict__ row, const int* __restrict__ col,
                               const int* __restrict__ rowstart, int* __restrict__ fill,
                               int* __restrict__ eidx, const float* __restrict__ dis,
                               float* __restrict__ sdis, int E) {
    int e = blockIdx.x * 256 + threadIdx.x;
    if (e < E) {
        int c = col[e];
        int r = row[e];
        int pos = rowstart[c] + atomicAdd(&fill[c], 1);
        eidx[pos] = r;
        atomicAdd(&sdis[c], dis[r]);
    }
}

__global__ void zrow_kernel(unsigned short* __restrict__ p, unsigned short* __restrict__ q) {
    p[threadIdx.x] = 0;                      // hws zero row (256)
    if (threadIdx.x < 64) q[threadIdx.x] = 0;  // xs zero row (64)
}

// xs[u] = dis[u] * x[u]  (bf16, N x 64)
__global__ void xs_kernel(const float* __restrict__ x, const float* __restrict__ dis,
                          unsigned short* __restrict__ xs, int total4) {
    int i4 = blockIdx.x * 256 + threadIdx.x;
    if (i4 < total4) {
        int i = i4 * 4;
        float d = dis[i >> 6];
        float4 v = *reinterpret_cast<const float4*>(x + i);
        *reinterpret_cast<uint2*>(xs + i) = pack4(d * v.x, d * v.y, d * v.z, d * v.w);
    }
}

// W96T[n][k] (bf16, 256 x 96): k<64 -> (node_w @ conv_w0)[k,n]; k==64 -> (node_b @ conv_w0)[n]; else 0
__global__ void wfuse_kernel(const float* __restrict__ nw, const float* __restrict__ nb,
                             const float* __restrict__ cw0, unsigned short* __restrict__ w96) {
    __shared__ float colv[256];
    int n = blockIdx.x, t = threadIdx.x;  // 128 threads
    colv[t] = cw0[t * 256 + n];
    colv[t + 128] = cw0[(t + 128) * 256 + n];
    __syncthreads();
    if (t < 64) {
        float acc = 0.0f;
        for (int j = 0; j < 256; j++) acc += nw[t * 256 + j] * colv[j];
        w96[n * 96 + t] = f2bf(acc);
    } else if (t == 64) {
        float acc = 0.0f;
        for (int j = 0; j < 256; j++) acc += nb[j] * colv[j];
        w96[n * 96 + t] = f2bf(acc);
    } else if (t < 96) {
        w96[n * 96 + t] = 0;
    }
}

// ---------------- GEMM (m97 recipe): C[M,Nc] = A[M,K] * BT[Nc,K]^T ----------------
// bf16 in, fp32 MFMA accumulate, bf16 out, optional bias[nc] / per-row scale[mr].
// Optionally zeroes stats[512] (block 0,0) for the next layer's agg.

__global__ __launch_bounds__(256)
void gemm_bt_kernel(const unsigned short* __restrict__ A, const unsigned short* __restrict__ BT,
                    unsigned short* __restrict__ C, const float* __restrict__ bias,
                    const float* __restrict__ scale, float* __restrict__ stats_clear,
                    int M, int K, int Nc) {
    __shared__ unsigned short As[128 * 32];
    __shared__ unsigned short Bs[128 * 32];

    if (stats_clear && blockIdx.x == 0 && blockIdx.y == 0) {
        stats_clear[threadIdx.x] = 0.0f;
        stats_clear[256 + threadIdx.x] = 0.0f;
    }

    const int lane = threadIdx.x & 63;
    const int wave = threadIdx.x >> 6;
    const int wm = wave >> 1, wn = wave & 1;
    const int r = lane & 15, q = lane >> 4;
    const int m0b = blockIdx.x * 128;
    const int n0b = blockIdx.y * 128;
    const int m0 = m0b + wm * 64;
    const int n0 = n0b + wn * 64;

    f32x4 acc[4][4] = {};

    for (int k0 = 0; k0 < K; k0 += 32) {
        __syncthreads();  // previous tile consumed
#pragma unroll
        for (int j = 0; j < 2; j++) {
            int s = threadIdx.x + j * 256;        // 512 slots of 16 B
            int row = s >> 2, kp = s & 3;
            int mr = m0b + row;
            if (mr >= M) mr = M - 1;
            const unsigned short* ga = A + (size_t)mr * K + k0 + kp * 8;
            __builtin_amdgcn_global_load_lds((const AS1 void*)ga, (AS3 void*)(As + s * 8), 16, 0, 0);
            int nr = n0b + row;                    // Nc is a multiple of 128
            const unsigned short* gb = BT + (size_t)nr * K + k0 + kp * 8;
            __builtin_amdgcn_global_load_lds((const AS1 void*)gb, (AS3 void*)(Bs + s * 8), 16, 0, 0);
        }
        __syncthreads();  // drains vmcnt -> LDS ready

        bf16x8 a[4], b[4];
#pragma unroll
        for (int i = 0; i < 4; i++)
            a[i] = *reinterpret_cast<const bf16x8*>(As + ((wm * 64 + i * 16 + r) * 32 + q * 8));
#pragma unroll
        for (int j = 0; j < 4; j++)
            b[j] = *reinterpret_cast<const bf16x8*>(Bs + ((wn * 64 + j * 16 + r) * 32 + q * 8));
#pragma unroll
        for (int i = 0; i < 4; i++)
#pragma unroll
            for (int j = 0; j < 4; j++)
                acc[i][j] = __builtin_amdgcn_mfma_f32_16x16x32_bf16(a[i], b[j], acc[i][j], 0, 0, 0);
    }

#pragma unroll
    for (int i = 0; i < 4; i++) {
#pragma unroll
        for (int t = 0; t < 4; t++) {
            int mr = m0 + i * 16 + q * 4 + t;  // C/D: row = q*4+reg, col = lane&15
            if (mr < M) {
                float rs = scale ? scale[mr] : 1.0f;
#pragma unroll
                for (int j = 0; j < 4; j++) {
                    int nc = n0 + j * 16 + r;
                    float v = acc[i][j][t] * rs;
                    if (bias) v += bias[nc];
                    C[(size_t)mr * Nc + nc] = f2bf(v);
                }
            }
        }
    }
}

// ---------------- aggx: layer-1 aggregation over xs (64 feats) -> y96 ----------------
// y[v] = dis_v * ( xs[v] + sum_{e: col=v} xs[src] ), s_v = dis_v*(dis_v + sdis[v])
// y96 row: [ y (64) | s (1) | 0 pad to 96 ]. xs[N] is a zero row.
// Wave handles 4 nodes; 8 lanes per edge (lane>>3 = edge slot, (lane&7)*8 = feature base).
// Ping-pong 16-edge buffers across nodes (R4 structure).

__global__ __launch_bounds__(256)
void aggx_kernel(const unsigned short* __restrict__ xs, const int* __restrict__ rowstart,
                 const int* __restrict__ eidx, const float* __restrict__ dis,
                 const float* __restrict__ sdis, unsigned short* __restrict__ y96, int N) {
    const int lane = threadIdx.x & 63;
    const int wave = threadIdx.x >> 6;
    const int slot = lane >> 3;       // 8 edges per round-pair
    const int fl = (lane & 7) * 8;    // 8 features per lane

    const int vb = __builtin_amdgcn_readfirstlane(blockIdx.x * 16 + wave * 4);

    int rs[5];
#pragma unroll
    for (int s = 0; s < 5; s++) rs[s] = rowstart[min(vb + s, N)];
    int js[4], de[4];
    float dvv[4], svv[4];
#pragma unroll
    for (int s = 0; s < 4; s++) {
        js[s] = rs[s];
        bool ok = (vb + s) < N;
        de[s] = ok ? (rs[s + 1] - rs[s]) : 0;
        float dv = ok ? dis[vb + s] : 0.0f;
        dvv[s] = dv;
        svv[s] = ok ? (dv * (dv + sdis[vb + s])) : 0.0f;
    }

    int idx0 = (lane < de[0]) ? eidx[js[0] + lane] : N;
    int idx1 = (lane < de[1]) ? eidx[js[1] + lane] : N;
    int idx2 = (lane < de[2]) ? eidx[js[2] + lane] : N;
    int idx3 = (lane < de[3]) ? eidx[js[3] + lane] : N;

    uint4 rA[2], rB[2];

    auto issue = [&](int myidx, uint4 (&rr)[2]) {
#pragma unroll
        for (int ro = 0; ro < 2; ro++) {
            int u = __shfl(myidx, ro * 8 + slot);
            rr[ro] = *reinterpret_cast<const uint4*>(xs + (size_t)u * 64 + fl);
        }
    };

    auto consume = [&](int s, int js_s, int d, float dv, float sv, int myidx, uint4 (&rr)[2]) {
        float a[8] = {};
#pragma unroll
        for (int ro = 0; ro < 2; ro++) {
            float x0, x1, x2, x3;
            unpack4(make_uint2(rr[ro].x, rr[ro].y), x0, x1, x2, x3);
            a[0] += x0; a[1] += x1; a[2] += x2; a[3] += x3;
            unpack4(make_uint2(rr[ro].z, rr[ro].w), x0, x1, x2, x3);
            a[4] += x0; a[5] += x1; a[6] += x2; a[7] += x3;
        }
        // rest of first chunk (deg > 16)
        int cnp = min(64, (d + 15) & ~15);
        for (int t = 16; t < cnp; t += 16) {
#pragma unroll
            for (int ro = 0; ro < 2; ro++) {
                int u = __shfl(myidx, t + ro * 8 + slot);
                rr[ro] = *reinterpret_cast<const uint4*>(xs + (size_t)u * 64 + fl);
            }
#pragma unroll
            for (int ro = 0; ro < 2; ro++) {
                float x0, x1, x2, x3;
                unpack4(make_uint2(rr[ro].x, rr[ro].y), x0, x1, x2, x3);
                a[0] += x0; a[1] += x1; a[2] += x2; a[3] += x3;
                unpack4(make_uint2(rr[ro].z, rr[ro].w), x0, x1, x2, x3);
                a[4] += x0; a[5] += x1; a[6] += x2; a[7] += x3;
            }
        }
        // chunks beyond 64 edges (rare)
        for (int base = 64; base < d; base += 64) {
            int mi = (base + lane < d) ? eidx[js_s + base + lane] : N;
            int cn2 = min(64, d - base);
            int cnp2 = (cn2 + 15) & ~15;
            for (int t = 0; t < cnp2; t += 16) {
#pragma unroll
                for (int ro = 0; ro < 2; ro++) {
                    int u = __shfl(mi, t + ro * 8 + slot);
                    rr[ro] = *reinterpret_cast<const uint4*>(xs + (size_t)u * 64 + fl);
                }
#pragma unroll
                for (int ro = 0; ro < 2; ro++) {
                    float x0, x1, x2, x3;
                    unpack4(make_uint2(rr[ro].x, rr[ro].y), x0, x1, x2, x3);
                    a[0] += x0; a[1] += x1; a[2] += x2; a[3] += x3;
                    unpack4(make_uint2(rr[ro].z, rr[ro].w), x0, x1, x2, x3);
                    a[4] += x0; a[5] += x1; a[6] += x2; a[7] += x3;
                }
            }
        }
        // reduce across 8 slots
#pragma unroll
        for (int j = 0; j < 8; j++) {
            a[j] += __shfl_xor(a[j], 8);
            a[j] += __shfl_xor(a[j], 16);
            a[j] += __shfl_xor(a[j], 32);
        }
        if ((vb + s) < N) {
            if (lane < 8) {
                // self + scale, write 8 features
                uint4 sr = *reinterpret_cast<const uint4*>(xs + (size_t)(vb + s) * 64 + fl);
                float x0, x1, x2, x3;
                unpack4(make_uint2(sr.x, sr.y), x0, x1, x2, x3);
                a[0] += x0; a[1] += x1; a[2] += x2; a[3] += x3;
                unpack4(make_uint2(sr.z, sr.w), x0, x1, x2, x3);
                a[4] += x0; a[5] += x1; a[6] += x2; a[7] += x3;
                uint2 lo = pack4(dv * a[0], dv * a[1], dv * a[2], dv * a[3]);
                uint2 hi = pack4(dv * a[4], dv * a[5], dv * a[6], dv * a[7]);
                *reinterpret_cast<uint4*>(y96 + (size_t)(vb + s) * 96 + fl) =
                    make_uint4(lo.x, lo.y, hi.x, hi.y);
            } else if (lane < 12) {
                unsigned sx = (lane == 8) ? (unsigned)f2bf(sv) : 0u;
                *reinterpret_cast<uint4*>(y96 + (size_t)(vb + s) * 96 + 64 + (lane - 8) * 8) =
                    make_uint4(sx, 0u, 0u, 0u);
            }
        }
    };

    issue(idx0, rA);
    issue(idx1, rB);
    consume(0, js[0], de[0], dvv[0], svv[0], idx0, rA);
    issue(idx2, rA);
    consume(1, js[1], de[1], dvv[1], svv[1], idx1, rB);
    issue(idx3, rB);
    consume(2, js[2], de[2], dvv[2], svv[2], idx2, rA);
    consume(3, js[3], de[3], dvv[3], svv[3], idx3, rB);
}

// ---------------- aggregation layers 2-3 (R4 ping-pong, measured-best) + fused BN stats ----------------

__global__ __launch_bounds__(256)
void agg_kernel(const unsigned short* __restrict__ hws, const int* __restrict__ rowstart,
                const int* __restrict__ eidx, const float* __restrict__ dis,
                const float* __restrict__ cb, unsigned short* __restrict__ agg,
                float* __restrict__ stats, int N) {
    __shared__ float s_sum[4][256];
    __shared__ float s_sq[4][256];
    const int lane = threadIdx.x & 63;
    const int wave = threadIdx.x >> 6;
    const int sub = lane >> 5;         // edge parity
    const int fl = (lane & 31) * 8;    // feature base (8 features per lane)

    const int vb = __builtin_amdgcn_readfirstlane(blockIdx.x * 16 + wave * 4);

    int rs[5];
#pragma unroll
    for (int s = 0; s < 5; s++) rs[s] = rowstart[min(vb + s, N)];
    int js[4], de[4];
    float dvv[4];
#pragma unroll
    for (int s = 0; s < 4; s++) {
        js[s] = rs[s];
        de[s] = (vb + s < N) ? (rs[s + 1] - rs[s]) : 0;
        dvv[s] = (vb + s < N) ? dis[vb + s] : 0.0f;
    }

    int idx0 = (lane < de[0]) ? eidx[js[0] + lane] : N;
    int idx1 = (lane < de[1]) ? eidx[js[1] + lane] : N;
    int idx2 = (lane < de[2]) ? eidx[js[2] + lane] : N;
    int idx3 = (lane < de[3]) ? eidx[js[3] + lane] : N;
    uint4 sf[4];
#pragma unroll
    for (int s = 0; s < 4; s++)
        sf[s] = *reinterpret_cast<const uint4*>(hws + (size_t)min(vb + s, N) * 256 + fl);

    float4 cbl = *reinterpret_cast<const float4*>(cb + fl);
    float4 cbh = *reinterpret_cast<const float4*>(cb + fl + 4);
    float c8[8] = {cbl.x, cbl.y, cbl.z, cbl.w, cbh.x, cbh.y, cbh.z, cbh.w};

    float ps[8] = {}, pq[8] = {};

    uint4 rA[8], rB[8];

    auto issue = [&](int myidx, uint4 (&rr)[8]) {
#pragma unroll
        for (int k = 0; k < 8; k++) {
            int u = __shfl(myidx, 2 * k + sub);
            rr[k] = *reinterpret_cast<const uint4*>(hws + (size_t)u * 256 + fl);
        }
    };

    auto consume = [&](int s, int js_s, int d, float dvs, int myidx, uint4 (&rr)[8]) {
        float a[8] = {};
#pragma unroll
        for (int k = 0; k < 8; k++) {
            float x0, x1, x2, x3;
            unpack4(make_uint2(rr[k].x, rr[k].y), x0, x1, x2, x3);
            a[0] += x0; a[1] += x1; a[2] += x2; a[3] += x3;
            unpack4(make_uint2(rr[k].z, rr[k].w), x0, x1, x2, x3);
            a[4] += x0; a[5] += x1; a[6] += x2; a[7] += x3;
        }
        int cnp = min(64, (d + 15) & ~15);
        for (int t = 16; t < cnp; t += 16) {
#pragma unroll
            for (int k = 0; k < 8; k++) {
                int u = __shfl(myidx, t + 2 * k + sub);
                rr[k] = *reinterpret_cast<const uint4*>(hws + (size_t)u * 256 + fl);
            }
#pragma unroll
            for (int k = 0; k < 8; k++) {
                float x0, x1, x2, x3;
                unpack4(make_uint2(rr[k].x, rr[k].y), x0, x1, x2, x3);
                a[0] += x0; a[1] += x1; a[2] += x2; a[3] += x3;
                unpack4(make_uint2(rr[k].z, rr[k].w), x0, x1, x2, x3);
                a[4] += x0; a[5] += x1; a[6] += x2; a[7] += x3;
            }
        }
        for (int base = 64; base < d; base += 64) {
            int mi = (base + lane < d) ? eidx[js_s + base + lane] : N;
            int cn2 = min(64, d - base);
            int cnp2 = (cn2 + 15) & ~15;
            for (int t = 0; t < cnp2; t += 16) {
#pragma unroll
                for (int k = 0; k < 8; k++) {
                    int u = __shfl(mi, t + 2 * k + sub);
                    rr[k] = *reinterpret_cast<const uint4*>(hws + (size_t)u * 256 + fl);
                }
#pragma unroll
                for (int k = 0; k < 8; k++) {
                    float x0, x1, x2, x3;
                    unpack4(make_uint2(rr[k].x, rr[k].y), x0, x1, x2, x3);
                    a[0] += x0; a[1] += x1; a[2] += x2; a[3] += x3;
                    unpack4(make_uint2(rr[k].z, rr[k].w), x0, x1, x2, x3);
                    a[4] += x0; a[5] += x1; a[6] += x2; a[7] += x3;
                }
            }
        }
#pragma unroll
        for (int j = 0; j < 8; j++) a[j] += __shfl_xor(a[j], 32);
        float x0, x1, x2, x3;
        unpack4(make_uint2(sf[s].x, sf[s].y), x0, x1, x2, x3);
        a[0] += x0; a[1] += x1; a[2] += x2; a[3] += x3;
        unpack4(make_uint2(sf[s].z, sf[s].w), x0, x1, x2, x3);
        a[4] += x0; a[5] += x1; a[6] += x2; a[7] += x3;
        float g[8];
#pragma unroll
        for (int j = 0; j < 8; j++) g[j] = c8[j] + dvs * a[j];
        if (vb + s < N && sub == 0) {
            uint2 lo = pack4(g[0], g[1], g[2], g[3]);
            uint2 hi = pack4(g[4], g[5], g[6], g[7]);
            *reinterpret_cast<uint4*>(agg + (size_t)(vb + s) * 256 + fl) =
                make_uint4(lo.x, lo.y, hi.x, hi.y);
#pragma unroll
            for (int j = 0; j < 8; j++) { ps[j] += g[j]; pq[j] += g[j] * g[j]; }
        }
    };

    issue(idx0, rA);
    issue(idx1, rB);
    consume(0, js[0], de[0], dvv[0], idx0, rA);
    issue(idx2, rA);
    consume(1, js[1], de[1], dvv[1], idx1, rB);
    issue(idx3, rB);
    consume(2, js[2], de[2], dvv[2], idx2, rA);
    consume(3, js[3], de[3], dvv[3], idx3, rB);

    if (sub == 0) {
#pragma unroll
        for (int j = 0; j < 8; j++) {
            s_sum[wave][fl + j] = ps[j];
            s_sq[wave][fl + j] = pq[j];
        }
    }
    __syncthreads();

    int f = threadIdx.x;
    float ts = s_sum[0][f] + s_sum[1][f] + s_sum[2][f] + s_sum[3][f];
    float tq = s_sq[0][f] + s_sq[1][f] + s_sq[2][f] + s_sq[3][f];
    atomicAdd(&stats[f], ts);
    atomicAdd(&stats[256 + f], tq);
}

// ---------------- stats over agg (layer 1, GEMM-produced) ----------------

__global__ __launch_bounds__(256)
void stats_kernel(const unsigned short* __restrict__ agg, float* __restrict__ stats, int N) {
    int f = threadIdx.x;
    int r0 = blockIdx.x * 32;
    int rows = min(32, N - r0);
    float ps = 0.0f, pq = 0.0f;
    for (int t = 0; t < rows; t++) {
        float v = bf2f(agg[(size_t)(r0 + t) * 256 + f]);
        ps += v; pq += v * v;
    }
    atomicAdd(&stats[f], ps);
    atomicAdd(&stats[256 + f], pq);
}

// ---------------- elem: BN affine (derived inline from stats) + ReLU -> bf16 h ----------------

__global__ __launch_bounds__(256)
void elem_kernel(const unsigned short* __restrict__ agg, const float* __restrict__ stats,
                 const float* __restrict__ bng, const float* __restrict__ bnb,
                 unsigned short* __restrict__ h, float inv_n, size_t total) {
    __shared__ float ssL[512];
    {
        int f = threadIdx.x;
        float mean = stats[f] * inv_n;
        float var = stats[256 + f] * inv_n - mean * mean;
        float sc = bng[f] * rsqrtf(var + 1e-5f);
        ssL[f] = sc;
        ssL[256 + f] = bnb[f] - mean * sc;
    }
    __syncthreads();
    size_t i = ((size_t)blockIdx.x * 256 + threadIdx.x) * 4;
    if (i < total) {
        float a0, a1, a2, a3;
        unpack4(*reinterpret_cast<const uint2*>(agg + i), a0, a1, a2, a3);
        int f = (int)(i & 255);
        float r0 = fmaxf(a0 * ssL[f] + ssL[256 + f], 0.0f);
        float r1 = fmaxf(a1 * ssL[f + 1] + ssL[256 + f + 1], 0.0f);
        float r2 = fmaxf(a2 * ssL[f + 2] + ssL[256 + f + 2], 0.0f);
        float r3 = fmaxf(a3 * ssL[f + 3] + ssL[256 + f + 3], 0.0f);
        *reinterpret_cast<uint2*>(h + i) = pack4(r0, r1, r2, r3);
    }
}

// ---------------- global_add_pool (batch is sorted) ----------------

__global__ __launch_bounds__(256)
void pool_kernel(const unsigned short* __restrict__ h, const int* __restrict__ batch,
                 float* __restrict__ g, int N) {
    __shared__ int sb[256];
    int f = threadIdx.x;
    int r0 = blockIdx.x * 256;
    int rows = min(256, N - r0);
    sb[f] = (r0 + f < N) ? batch[r0 + f] : -1;
    __syncthreads();
    float acc = 0.0f;
    int cur = sb[0];
    for (int t = 0; t < rows; t++) {
        int b = sb[t];
        if (b != cur) {
            atomicAdd(&g[cur * 256 + f], acc);
            acc = 0.0f;
            cur = b;
        }
        acc += bf2f(h[(size_t)(r0 + t) * 256 + f]);
    }
    atomicAdd(&g[cur * 256 + f], acc);
}

// ---------------- head MLP: relu(g@w1+b1)@w2+b2 ----------------

__global__ void head_kernel(const float* __restrict__ g, const float* __restrict__ w1,
                            const float* __restrict__ b1, const float* __restrict__ w2,
                            const float* __restrict__ b2, float* __restrict__ out) {
    __shared__ float gr[256];
    __shared__ float z[128];
    int b = blockIdx.x, t = threadIdx.x;
    gr[t] = g[b * 256 + t];
    gr[t + 128] = g[b * 256 + 128 + t];
    __syncthreads();
    float acc = b1[t];
    for (int k = 0; k < 256; k++) acc += gr[k] * w1[k * 128 + t];
    z[t] = fmaxf(acc, 0.0f);
    __syncthreads();
    if (t < 12) {
        float o = b2[t];
        for (int k = 0; k < 128; k++) o += z[k] * w2[k * 12 + t];
        out[b * 12 + t] = o;
    }
}

// ---------------- launch ----------------

extern "C" void kernel_launch(void* const* d_in, const int* in_sizes, int n_in,
                              void* d_out, int out_size, void* d_ws, size_t ws_size,
                              hipStream_t stream) {
    const float* x      = (const float*)d_in[0];
    const int*   ei     = (const int*)d_in[1];
    const int*   batch  = (const int*)d_in[2];
    const float* node_w = (const float*)d_in[3];
    const float* node_b = (const float*)d_in[4];
    const float* conv_w = (const float*)d_in[5];
    const float* conv_b = (const float*)d_in[6];
    const float* bn_g   = (const float*)d_in[7];
    const float* bn_b   = (const float*)d_in[8];
    const float* hw1    = (const float*)d_in[9];
    const float* hb1    = (const float*)d_in[10];
    const float* hw2    = (const float*)d_in[11];
    const float* hb2    = (const float*)d_in[12];
    float* out = (float*)d_out;

    const int N = in_sizes[2];
    const int E = in_sizes[1] / 2;
    const int H = 256;
    const float inv_n = 1.0f / (float)N;

    char* base = (char*)d_ws;
    size_t off = 0;
    auto alloc = [&](size_t bytes) -> void* {
        off = (off + 255) & ~(size_t)255;
        void* p = base + off;
        off += bytes;
        return p;
    };
    unsigned short* xs  = (unsigned short*)alloc((size_t)(N + 1) * 64 * 2);   // +1 zero row
    unsigned short* y96 = (unsigned short*)alloc((size_t)N * 96 * 2);
    unsigned short* w96 = (unsigned short*)alloc((size_t)256 * 96 * 2);
    unsigned short* h   = (unsigned short*)alloc((size_t)N * H * 2);
    unsigned short* hws = (unsigned short*)alloc((size_t)(N + 1) * H * 2);    // +1 zero row
    unsigned short* agg = (unsigned short*)alloc((size_t)N * H * 2);
    unsigned short* cwT = (unsigned short*)alloc((size_t)3 * H * H * 2);
    int* cnt      = (int*)alloc((size_t)N * 4);
    int* fill     = (int*)alloc((size_t)N * 4);
    int* rowstart = (int*)alloc((size_t)(N + 1) * 4);
    int* scanbuf  = (int*)alloc((size_t)N * 4);
    int* bsum     = (int*)alloc(1024);
    int* boff     = (int*)alloc(1024);
    int* eidx     = (int*)alloc((size_t)(E + 64) * 4);  // +64 pad
    float* dis    = (float*)alloc((size_t)N * 4);
    float* sdis   = (float*)alloc((size_t)N * 4);
    float* stats  = (float*)alloc(512 * 4);
    float* gpool  = (float*)alloc(64 * H * 4);

    const int* row = ei;
    const int* col = ei + E;

    hipMemsetAsync(cnt, 0, (size_t)N * 4, stream);
    hipMemsetAsync(fill, 0, (size_t)N * 4, stream);
    hipMemsetAsync(sdis, 0, (size_t)N * 4, stream);
    hipMemsetAsync(stats, 0, 512 * 4, stream);
    zrow_kernel<<<dim3(1), 256, 0, stream>>>(hws + (size_t)N * H, xs + (size_t)N * 64);

    prep_kernel<<<dim3(3 * H * H / 256), 256, 0, stream>>>(conv_w, cwT);
    wfuse_kernel<<<dim3(256), 128, 0, stream>>>(node_w, node_b, conv_w, w96);

    deg_kernel<<<dim3((E + 255) / 256), 256, 0, stream>>>(col, cnt, E);
    int nb = (N + 511) / 512;
    scan1_kernel<<<dim3(nb), 512, 0, stream>>>(cnt, scanbuf, bsum, dis, N);
    scan2_kernel<<<dim3(1), 64, 0, stream>>>(bsum, boff, nb);
    scan3_kernel<<<dim3((N + 255) / 256), 256, 0, stream>>>(scanbuf, boff, rowstart, N);
    scatter_kernel<<<dim3((E + 255) / 256), 256, 0, stream>>>(row, col, rowstart, fill, eidx,
                                                              dis, sdis, E);
    xs_kernel<<<dim3((N * 64 / 4 + 255) / 256), 256, 0, stream>>>(x, dis, xs, N * 64 / 4);

    // layer 1: aggregate xs -> y96, then single K=96 GEMM (bias = conv_b[0])
    aggx_kernel<<<dim3((N + 15) / 16), 256, 0, stream>>>(xs, rowstart, eidx, dis, sdis, y96, N);
    dim3 gg((N + 127) / 128, H / 128);
    gemm_bt_kernel<<<gg, 256, 0, stream>>>(y96, w96, agg, conv_b, nullptr, nullptr, N, 96, H);
    stats_kernel<<<dim3((N + 31) / 32), 256, 0, stream>>>(agg, stats, N);
    elem_kernel<<<dim3((int)(((size_t)N * H / 4 + 255) / 256)), 256, 0, stream>>>(
        agg, stats, bn_g, bn_b, h, inv_n, (size_t)N * H);

    // layers 2-3
    for (int l = 1; l < 3; l++) {
        gemm_bt_kernel<<<gg, 256, 0, stream>>>(h, cwT + (size_t)l * H * H, hws, nullptr, dis,
                                               stats, N, H, H);
        agg_kernel<<<dim3((N + 15) / 16), 256, 0, stream>>>(hws, rowstart, eidx, dis,
                                                            conv_b + l * H, agg, stats, N);
        elem_kernel<<<dim3((int)(((size_t)N * H / 4 + 255) / 256)), 256, 0, stream>>>(
            agg, stats, bn_g + l * H, bn_b + l * H, h, inv_n, (size_t)N * H);
    }

    hipMemsetAsync(gpool, 0, 64 * H * 4, stream);
    pool_kernel<<<dim3((N + 255) / 256), 256, 0, stream>>>(h, batch, gpool, N);
    head_kernel<<<dim3(64), 128, 0, stream>>>(gpool, hw1, hb1, hw2, hb2, out);
}

// Round 9
// 575.359 us; speedup vs baseline: 5.1670x; 1.1188x over previous
//
#include <hip/hip_runtime.h>
#include <stdint.h>

#define AS1 __attribute__((address_space(1)))
#define AS3 __attribute__((address_space(3)))

typedef __bf16 bf16x8 __attribute__((ext_vector_type(8)));
typedef float f32x4 __attribute__((ext_vector_type(4)));

__device__ __forceinline__ float bf2f(unsigned short u) {
    return __uint_as_float(((unsigned)u) << 16);
}
__device__ __forceinline__ unsigned short f2bf(float f) {
    unsigned u = __float_as_uint(f);
    unsigned r = u + 0x7fffu + ((u >> 16) & 1u);  // RNE
    return (unsigned short)(r >> 16);
}
__device__ __forceinline__ void unpack4(uint2 u, float& a, float& b, float& c, float& d) {
    a = __uint_as_float(u.x << 16);
    b = __uint_as_float(u.x & 0xffff0000u);
    c = __uint_as_float(u.y << 16);
    d = __uint_as_float(u.y & 0xffff0000u);
}
__device__ __forceinline__ uint2 pack4(float a, float b, float c, float d) {
    uint2 o;
    o.x = (unsigned)f2bf(a) | ((unsigned)f2bf(b) << 16);
    o.y = (unsigned)f2bf(c) | ((unsigned)f2bf(d) << 16);
    return o;
}

// ---------------- prep: transpose conv_w; last block zeroes the pad rows ----------------

__global__ void prep_kernel(const float* __restrict__ cw, unsigned short* __restrict__ cwT,
                            unsigned short* __restrict__ hz, unsigned short* __restrict__ xz) {
    int b = blockIdx.x;
    if (b == gridDim.x - 1) {
        hz[threadIdx.x] = 0;
        if (threadIdx.x < 64) xz[threadIdx.x] = 0;
        return;
    }
    int idx = b * 256 + threadIdx.x;  // over 3*256*256
    int l = idx >> 16, rem = idx & 65535;
    int k = rem >> 8, n = rem & 255;
    cwT[(l << 16) + (n << 8) + k] = f2bf(cw[idx]);
}

// ---------------- degree / CSR build ----------------

__global__ void deg_kernel(const int* __restrict__ col, int* __restrict__ cnt, int E) {
    int e = blockIdx.x * 256 + threadIdx.x;
    if (e < E) atomicAdd(&cnt[col[e]], 1);
}

__global__ void scan1_kernel(const int* __restrict__ cnt, int* __restrict__ scanbuf,
                             int* __restrict__ bsum, float* __restrict__ dis, int N) {
    __shared__ int s[512];
    int i = blockIdx.x * 512 + threadIdx.x;
    int c = (i < N) ? cnt[i] : 0;
    if (i < N) dis[i] = rsqrtf((float)c + 1.0f);  // +1 self-loop
    s[threadIdx.x] = c;
    __syncthreads();
    for (int off = 1; off < 512; off <<= 1) {
        int t = (threadIdx.x >= off) ? s[threadIdx.x - off] : 0;
        __syncthreads();
        s[threadIdx.x] += t;
        __syncthreads();
    }
    if (i < N) scanbuf[i] = s[threadIdx.x];
    if (threadIdx.x == 511) bsum[blockIdx.x] = s[511];
}

__global__ void scan2_kernel(const int* __restrict__ bsum, int* __restrict__ boff, int nb) {
    __shared__ int s[128];
    int t = threadIdx.x;
    int v = (t < nb) ? bsum[t] : 0;
    s[t] = v;
    __syncthreads();
    for (int off = 1; off < 128; off <<= 1) {
        int u = (t >= off) ? s[t - off] : 0;
        __syncthreads();
        s[t] += u;
        __syncthreads();
    }
    if (t < nb) boff[t] = s[t] - v;  // exclusive
}

__global__ void scan3_kernel(const int* __restrict__ scanbuf, const int* __restrict__ boff,
                             int* __restrict__ rowstart, int N) {
    int i = blockIdx.x * 256 + threadIdx.x;
    if (i < N) rowstart[i + 1] = scanbuf[i] + boff[i >> 9];
    if (i == 0) rowstart[0] = 0;
}

// scatter edges into CSR; also accumulate sdis[v] = sum of dis[src] over in-edges
__global__ void scatter_kernel(const int* __restrict__ row, const int* __restrict__ col,
                               const int* __restrict__ rowstart, int* __restrict__ fill,
                               int* __restrict__ eidx, const float* __restrict__ dis,
                               float* __restrict__ sdis, int E) {
    int e = blockIdx.x * 256 + threadIdx.x;
    if (e < E) {
        int c = col[e];
        int r = row[e];
        int pos = rowstart[c] + atomicAdd(&fill[c], 1);
        eidx[pos] = r;
        atomicAdd(&sdis[c], dis[r]);
    }
}

// xs[u] = dis[u] * x[u]  (bf16, N x 64)
__global__ void xs_kernel(const float* __restrict__ x, const float* __restrict__ dis,
                          unsigned short* __restrict__ xs, int total4) {
    int i4 = blockIdx.x * 256 + threadIdx.x;
    if (i4 < total4) {
        int i = i4 * 4;
        float d = dis[i >> 6];
        float4 v = *reinterpret_cast<const float4*>(x + i);
        *reinterpret_cast<uint2*>(xs + i) = pack4(d * v.x, d * v.y, d * v.z, d * v.w);
    }
}

// W96T[n][k] (bf16, 256 x 96): k<64 -> (node_w @ conv_w0)[k,n]; k==64 -> (node_b @ conv_w0)[n]; else 0
__global__ void wfuse_kernel(const float* __restrict__ nw, const float* __restrict__ nb,
                             const float* __restrict__ cw0, unsigned short* __restrict__ w96) {
    __shared__ float colv[256];
    int n = blockIdx.x, t = threadIdx.x;  // 128 threads
    colv[t] = cw0[t * 256 + n];
    colv[t + 128] = cw0[(t + 128) * 256 + n];
    __syncthreads();
    if (t < 64) {
        float acc = 0.0f;
        for (int j = 0; j < 256; j++) acc += nw[t * 256 + j] * colv[j];
        w96[n * 96 + t] = f2bf(acc);
    } else if (t == 64) {
        float acc = 0.0f;
        for (int j = 0; j < 256; j++) acc += nb[j] * colv[j];
        w96[n * 96 + t] = f2bf(acc);
    } else if (t < 96) {
        w96[n * 96 + t] = 0;
    }
}

// ---------------- GEMM (m97 recipe): C[M,Nc] = A[M,K] * BT[Nc,K]^T ----------------

__global__ __launch_bounds__(256)
void gemm_bt_kernel(const unsigned short* __restrict__ A, const unsigned short* __restrict__ BT,
                    unsigned short* __restrict__ C, const float* __restrict__ bias,
                    const float* __restrict__ scale, float* __restrict__ stats_clear,
                    int M, int K, int Nc) {
    __shared__ unsigned short As[128 * 32];
    __shared__ unsigned short Bs[128 * 32];

    if (stats_clear && blockIdx.x == 0 && blockIdx.y == 0) {
        stats_clear[threadIdx.x] = 0.0f;
        stats_clear[256 + threadIdx.x] = 0.0f;
    }

    const int lane = threadIdx.x & 63;
    const int wave = threadIdx.x >> 6;
    const int wm = wave >> 1, wn = wave & 1;
    const int r = lane & 15, q = lane >> 4;
    const int m0b = blockIdx.x * 128;
    const int n0b = blockIdx.y * 128;
    const int m0 = m0b + wm * 64;
    const int n0 = n0b + wn * 64;

    f32x4 acc[4][4] = {};

    for (int k0 = 0; k0 < K; k0 += 32) {
        __syncthreads();  // previous tile consumed
#pragma unroll
        for (int j = 0; j < 2; j++) {
            int s = threadIdx.x + j * 256;        // 512 slots of 16 B
            int row = s >> 2, kp = s & 3;
            int mr = m0b + row;
            if (mr >= M) mr = M - 1;
            const unsigned short* ga = A + (size_t)mr * K + k0 + kp * 8;
            __builtin_amdgcn_global_load_lds((const AS1 void*)ga, (AS3 void*)(As + s * 8), 16, 0, 0);
            int nr = n0b + row;                    // Nc is a multiple of 128
            const unsigned short* gb = BT + (size_t)nr * K + k0 + kp * 8;
            __builtin_amdgcn_global_load_lds((const AS1 void*)gb, (AS3 void*)(Bs + s * 8), 16, 0, 0);
        }
        __syncthreads();  // drains vmcnt -> LDS ready

        bf16x8 a[4], b[4];
#pragma unroll
        for (int i = 0; i < 4; i++)
            a[i] = *reinterpret_cast<const bf16x8*>(As + ((wm * 64 + i * 16 + r) * 32 + q * 8));
#pragma unroll
        for (int j = 0; j < 4; j++)
            b[j] = *reinterpret_cast<const bf16x8*>(Bs + ((wn * 64 + j * 16 + r) * 32 + q * 8));
#pragma unroll
        for (int i = 0; i < 4; i++)
#pragma unroll
            for (int j = 0; j < 4; j++)
                acc[i][j] = __builtin_amdgcn_mfma_f32_16x16x32_bf16(a[i], b[j], acc[i][j], 0, 0, 0);
    }

#pragma unroll
    for (int i = 0; i < 4; i++) {
#pragma unroll
        for (int t = 0; t < 4; t++) {
            int mr = m0 + i * 16 + q * 4 + t;  // C/D: row = q*4+reg, col = lane&15
            if (mr < M) {
                float rs = scale ? scale[mr] : 1.0f;
#pragma unroll
                for (int j = 0; j < 4; j++) {
                    int nc = n0 + j * 16 + r;
                    float v = acc[i][j][t] * rs;
                    if (bias) v += bias[nc];
                    C[(size_t)mr * Nc + nc] = f2bf(v);
                }
            }
        }
    }
}

// ---------------- aggx: layer-1 aggregation over xs (64 feats) -> y96 ----------------
// Triple-buffered: loads for 2 nodes ahead always in flight; self rows prefetched.

__global__ __launch_bounds__(256)
void aggx_kernel(const unsigned short* __restrict__ xs, const int* __restrict__ rowstart,
                 const int* __restrict__ eidx, const float* __restrict__ dis,
                 const float* __restrict__ sdis, unsigned short* __restrict__ y96, int N) {
    const int lane = threadIdx.x & 63;
    const int wave = threadIdx.x >> 6;
    const int slot = lane >> 3;       // 8 edges per round
    const int fl = (lane & 7) * 8;    // 8 features per lane

    const int vb = __builtin_amdgcn_readfirstlane(blockIdx.x * 16 + wave * 4);

    int rs[5];
#pragma unroll
    for (int s = 0; s < 5; s++) rs[s] = rowstart[min(vb + s, N)];
    int js[4], de[4];
    float dvv[4], svv[4];
#pragma unroll
    for (int s = 0; s < 4; s++) {
        js[s] = rs[s];
        bool ok = (vb + s) < N;
        de[s] = ok ? (rs[s + 1] - rs[s]) : 0;
        float dv = ok ? dis[vb + s] : 0.0f;
        dvv[s] = dv;
        svv[s] = ok ? (dv * (dv + sdis[vb + s])) : 0.0f;
    }

    int idx0 = (lane < de[0]) ? eidx[js[0] + lane] : N;
    int idx1 = (lane < de[1]) ? eidx[js[1] + lane] : N;
    int idx2 = (lane < de[2]) ? eidx[js[2] + lane] : N;
    int idx3 = (lane < de[3]) ? eidx[js[3] + lane] : N;

    uint4 sf[4];
#pragma unroll
    for (int s = 0; s < 4; s++)
        sf[s] = *reinterpret_cast<const uint4*>(xs + (size_t)min(vb + s, N) * 64 + fl);

    uint4 rA[2], rB[2], rC[2];

    auto issue = [&](int myidx, uint4 (&rr)[2]) {
#pragma unroll
        for (int ro = 0; ro < 2; ro++) {
            int u = __shfl(myidx, ro * 8 + slot);
            rr[ro] = *reinterpret_cast<const uint4*>(xs + (size_t)u * 64 + fl);
        }
    };

    auto consume = [&](int s, int js_s, int d, float dv, float sv, int myidx, uint4 (&rr)[2]) {
        float a[8] = {};
#pragma unroll
        for (int ro = 0; ro < 2; ro++) {
            float x0, x1, x2, x3;
            unpack4(make_uint2(rr[ro].x, rr[ro].y), x0, x1, x2, x3);
            a[0] += x0; a[1] += x1; a[2] += x2; a[3] += x3;
            unpack4(make_uint2(rr[ro].z, rr[ro].w), x0, x1, x2, x3);
            a[4] += x0; a[5] += x1; a[6] += x2; a[7] += x3;
        }
        // rest of first chunk (deg > 16)
        int cnp = min(64, (d + 15) & ~15);
        for (int t = 16; t < cnp; t += 16) {
#pragma unroll
            for (int ro = 0; ro < 2; ro++) {
                int u = __shfl(myidx, t + ro * 8 + slot);
                rr[ro] = *reinterpret_cast<const uint4*>(xs + (size_t)u * 64 + fl);
            }
#pragma unroll
            for (int ro = 0; ro < 2; ro++) {
                float x0, x1, x2, x3;
                unpack4(make_uint2(rr[ro].x, rr[ro].y), x0, x1, x2, x3);
                a[0] += x0; a[1] += x1; a[2] += x2; a[3] += x3;
                unpack4(make_uint2(rr[ro].z, rr[ro].w), x0, x1, x2, x3);
                a[4] += x0; a[5] += x1; a[6] += x2; a[7] += x3;
            }
        }
        // chunks beyond 64 edges (rare)
        for (int base = 64; base < d; base += 64) {
            int mi = (base + lane < d) ? eidx[js_s + base + lane] : N;
            int cn2 = min(64, d - base);
            int cnp2 = (cn2 + 15) & ~15;
            for (int t = 0; t < cnp2; t += 16) {
#pragma unroll
                for (int ro = 0; ro < 2; ro++) {
                    int u = __shfl(mi, t + ro * 8 + slot);
                    rr[ro] = *reinterpret_cast<const uint4*>(xs + (size_t)u * 64 + fl);
                }
#pragma unroll
                for (int ro = 0; ro < 2; ro++) {
                    float x0, x1, x2, x3;
                    unpack4(make_uint2(rr[ro].x, rr[ro].y), x0, x1, x2, x3);
                    a[0] += x0; a[1] += x1; a[2] += x2; a[3] += x3;
                    unpack4(make_uint2(rr[ro].z, rr[ro].w), x0, x1, x2, x3);
                    a[4] += x0; a[5] += x1; a[6] += x2; a[7] += x3;
                }
            }
        }
        // reduce across 8 slots
#pragma unroll
        for (int j = 0; j < 8; j++) {
            a[j] += __shfl_xor(a[j], 8);
            a[j] += __shfl_xor(a[j], 16);
            a[j] += __shfl_xor(a[j], 32);
        }
        if ((vb + s) < N) {
            if (lane < 8) {
                float x0, x1, x2, x3;
                unpack4(make_uint2(sf[s].x, sf[s].y), x0, x1, x2, x3);
                a[0] += x0; a[1] += x1; a[2] += x2; a[3] += x3;
                unpack4(make_uint2(sf[s].z, sf[s].w), x0, x1, x2, x3);
                a[4] += x0; a[5] += x1; a[6] += x2; a[7] += x3;
                uint2 lo = pack4(dv * a[0], dv * a[1], dv * a[2], dv * a[3]);
                uint2 hi = pack4(dv * a[4], dv * a[5], dv * a[6], dv * a[7]);
                *reinterpret_cast<uint4*>(y96 + (size_t)(vb + s) * 96 + fl) =
                    make_uint4(lo.x, lo.y, hi.x, hi.y);
            } else if (lane < 12) {
                unsigned sx = (lane == 8) ? (unsigned)f2bf(sv) : 0u;
                *reinterpret_cast<uint4*>(y96 + (size_t)(vb + s) * 96 + 64 + (lane - 8) * 8) =
                    make_uint4(sx, 0u, 0u, 0u);
            }
        }
    };

    issue(idx0, rA);
    issue(idx1, rB);
    issue(idx2, rC);
    consume(0, js[0], de[0], dvv[0], svv[0], idx0, rA);
    issue(idx3, rA);
    consume(1, js[1], de[1], dvv[1], svv[1], idx1, rB);
    consume(2, js[2], de[2], dvv[2], svv[2], idx2, rC);
    consume(3, js[3], de[3], dvv[3], svv[3], idx3, rA);
}

// ---------------- aggregation layers 2-3 (R4 ping-pong, measured-best) + fused BN stats ----------------

__global__ __launch_bounds__(256)
void agg_kernel(const unsigned short* __restrict__ hws, const int* __restrict__ rowstart,
                const int* __restrict__ eidx, const float* __restrict__ dis,
                const float* __restrict__ cb, unsigned short* __restrict__ agg,
                float* __restrict__ stats, int N) {
    __shared__ float s_sum[4][256];
    __shared__ float s_sq[4][256];
    const int lane = threadIdx.x & 63;
    const int wave = threadIdx.x >> 6;
    const int sub = lane >> 5;         // edge parity
    const int fl = (lane & 31) * 8;    // feature base (8 features per lane)

    const int vb = __builtin_amdgcn_readfirstlane(blockIdx.x * 16 + wave * 4);

    int rs[5];
#pragma unroll
    for (int s = 0; s < 5; s++) rs[s] = rowstart[min(vb + s, N)];
    int js[4], de[4];
    float dvv[4];
#pragma unroll
    for (int s = 0; s < 4; s++) {
        js[s] = rs[s];
        de[s] = (vb + s < N) ? (rs[s + 1] - rs[s]) : 0;
        dvv[s] = (vb + s < N) ? dis[vb + s] : 0.0f;
    }

    int idx0 = (lane < de[0]) ? eidx[js[0] + lane] : N;
    int idx1 = (lane < de[1]) ? eidx[js[1] + lane] : N;
    int idx2 = (lane < de[2]) ? eidx[js[2] + lane] : N;
    int idx3 = (lane < de[3]) ? eidx[js[3] + lane] : N;
    uint4 sf[4];
#pragma unroll
    for (int s = 0; s < 4; s++)
        sf[s] = *reinterpret_cast<const uint4*>(hws + (size_t)min(vb + s, N) * 256 + fl);

    float4 cbl = *reinterpret_cast<const float4*>(cb + fl);
    float4 cbh = *reinterpret_cast<const float4*>(cb + fl + 4);
    float c8[8] = {cbl.x, cbl.y, cbl.z, cbl.w, cbh.x, cbh.y, cbh.z, cbh.w};

    float ps[8] = {}, pq[8] = {};

    uint4 rA[8], rB[8];

    auto issue = [&](int myidx, uint4 (&rr)[8]) {
#pragma unroll
        for (int k = 0; k < 8; k++) {
            int u = __shfl(myidx, 2 * k + sub);
            rr[k] = *reinterpret_cast<const uint4*>(hws + (size_t)u * 256 + fl);
        }
    };

    auto consume = [&](int s, int js_s, int d, float dvs, int myidx, uint4 (&rr)[8]) {
        float a[8] = {};
#pragma unroll
        for (int k = 0; k < 8; k++) {
            float x0, x1, x2, x3;
            unpack4(make_uint2(rr[k].x, rr[k].y), x0, x1, x2, x3);
            a[0] += x0; a[1] += x1; a[2] += x2; a[3] += x3;
            unpack4(make_uint2(rr[k].z, rr[k].w), x0, x1, x2, x3);
            a[4] += x0; a[5] += x1; a[6] += x2; a[7] += x3;
        }
        int cnp = min(64, (d + 15) & ~15);
        for (int t = 16; t < cnp; t += 16) {
#pragma unroll
            for (int k = 0; k < 8; k++) {
                int u = __shfl(myidx, t + 2 * k + sub);
                rr[k] = *reinterpret_cast<const uint4*>(hws + (size_t)u * 256 + fl);
            }
#pragma unroll
            for (int k = 0; k < 8; k++) {
                float x0, x1, x2, x3;
                unpack4(make_uint2(rr[k].x, rr[k].y), x0, x1, x2, x3);
                a[0] += x0; a[1] += x1; a[2] += x2; a[3] += x3;
                unpack4(make_uint2(rr[k].z, rr[k].w), x0, x1, x2, x3);
                a[4] += x0; a[5] += x1; a[6] += x2; a[7] += x3;
            }
        }
        for (int base = 64; base < d; base += 64) {
            int mi = (base + lane < d) ? eidx[js_s + base + lane] : N;
            int cn2 = min(64, d - base);
            int cnp2 = (cn2 + 15) & ~15;
            for (int t = 0; t < cnp2; t += 16) {
#pragma unroll
                for (int k = 0; k < 8; k++) {
                    int u = __shfl(mi, t + 2 * k + sub);
                    rr[k] = *reinterpret_cast<const uint4*>(hws + (size_t)u * 256 + fl);
                }
#pragma unroll
                for (int k = 0; k < 8; k++) {
                    float x0, x1, x2, x3;
                    unpack4(make_uint2(rr[k].x, rr[k].y), x0, x1, x2, x3);
                    a[0] += x0; a[1] += x1; a[2] += x2; a[3] += x3;
                    unpack4(make_uint2(rr[k].z, rr[k].w), x0, x1, x2, x3);
                    a[4] += x0; a[5] += x1; a[6] += x2; a[7] += x3;
                }
            }
        }
#pragma unroll
        for (int j = 0; j < 8; j++) a[j] += __shfl_xor(a[j], 32);
        float x0, x1, x2, x3;
        unpack4(make_uint2(sf[s].x, sf[s].y), x0, x1, x2, x3);
        a[0] += x0; a[1] += x1; a[2] += x2; a[3] += x3;
        unpack4(make_uint2(sf[s].z, sf[s].w), x0, x1, x2, x3);
        a[4] += x0; a[5] += x1; a[6] += x2; a[7] += x3;
        float g[8];
#pragma unroll
        for (int j = 0; j < 8; j++) g[j] = c8[j] + dvs * a[j];
        if (vb + s < N && sub == 0) {
            uint2 lo = pack4(g[0], g[1], g[2], g[3]);
            uint2 hi = pack4(g[4], g[5], g[6], g[7]);
            *reinterpret_cast<uint4*>(agg + (size_t)(vb + s) * 256 + fl) =
                make_uint4(lo.x, lo.y, hi.x, hi.y);
#pragma unroll
            for (int j = 0; j < 8; j++) { ps[j] += g[j]; pq[j] += g[j] * g[j]; }
        }
    };

    issue(idx0, rA);
    issue(idx1, rB);
    consume(0, js[0], de[0], dvv[0], idx0, rA);
    issue(idx2, rA);
    consume(1, js[1], de[1], dvv[1], idx1, rB);
    issue(idx3, rB);
    consume(2, js[2], de[2], dvv[2], idx2, rA);
    consume(3, js[3], de[3], dvv[3], idx3, rB);

    if (sub == 0) {
#pragma unroll
        for (int j = 0; j < 8; j++) {
            s_sum[wave][fl + j] = ps[j];
            s_sq[wave][fl + j] = pq[j];
        }
    }
    __syncthreads();

    int f = threadIdx.x;
    float ts = s_sum[0][f] + s_sum[1][f] + s_sum[2][f] + s_sum[3][f];
    float tq = s_sq[0][f] + s_sq[1][f] + s_sq[2][f] + s_sq[3][f];
    atomicAdd(&stats[f], ts);
    atomicAdd(&stats[256 + f], tq);
}

// ---------------- stats over agg (layer 1, GEMM-produced) ----------------

__global__ __launch_bounds__(256)
void stats_kernel(const unsigned short* __restrict__ agg, float* __restrict__ stats, int N) {
    int f = threadIdx.x;
    int r0 = blockIdx.x * 32;
    int rows = min(32, N - r0);
    float ps = 0.0f, pq = 0.0f;
    for (int t = 0; t < rows; t++) {
        float v = bf2f(agg[(size_t)(r0 + t) * 256 + f]);
        ps += v; pq += v * v;
    }
    atomicAdd(&stats[f], ps);
    atomicAdd(&stats[256 + f], pq);
}

// ---------------- elem: BN affine (derived inline from stats) + ReLU -> bf16 h ----------------

__global__ __launch_bounds__(256)
void elem_kernel(const unsigned short* __restrict__ agg, const float* __restrict__ stats,
                 const float* __restrict__ bng, const float* __restrict__ bnb,
                 unsigned short* __restrict__ h, float inv_n, size_t total) {
    __shared__ float ssL[512];
    {
        int f = threadIdx.x;
        float mean = stats[f] * inv_n;
        float var = stats[256 + f] * inv_n - mean * mean;
        float sc = bng[f] * rsqrtf(var + 1e-5f);
        ssL[f] = sc;
        ssL[256 + f] = bnb[f] - mean * sc;
    }
    __syncthreads();
    size_t i = ((size_t)blockIdx.x * 256 + threadIdx.x) * 4;
    if (i < total) {
        float a0, a1, a2, a3;
        unpack4(*reinterpret_cast<const uint2*>(agg + i), a0, a1, a2, a3);
        int f = (int)(i & 255);
        float r0 = fmaxf(a0 * ssL[f] + ssL[256 + f], 0.0f);
        float r1 = fmaxf(a1 * ssL[f + 1] + ssL[256 + f + 1], 0.0f);
        float r2 = fmaxf(a2 * ssL[f + 2] + ssL[256 + f + 2], 0.0f);
        float r3 = fmaxf(a3 * ssL[f + 3] + ssL[256 + f + 3], 0.0f);
        *reinterpret_cast<uint2*>(h + i) = pack4(r0, r1, r2, r3);
    }
}

// ---------------- global_add_pool (batch sorted; 32 rows/block) ----------------

__global__ __launch_bounds__(256)
void pool_kernel(const unsigned short* __restrict__ h, const int* __restrict__ batch,
                 float* __restrict__ g, int N) {
    __shared__ int sb[32];
    int f = threadIdx.x;
    int r0 = blockIdx.x * 32;
    int rows = min(32, N - r0);
    if (f < 32) sb[f] = (r0 + f < N) ? batch[r0 + f] : -1;
    __syncthreads();
    float acc = 0.0f;
    int cur = sb[0];
    for (int t = 0; t < rows; t++) {
        int b = sb[t];
        if (b != cur) {
            atomicAdd(&g[cur * 256 + f], acc);
            acc = 0.0f;
            cur = b;
        }
        acc += bf2f(h[(size_t)(r0 + t) * 256 + f]);
    }
    atomicAdd(&g[cur * 256 + f], acc);
}

// ---------------- head MLP: relu(g@w1+b1)@w2+b2 ----------------

__global__ void head_kernel(const float* __restrict__ g, const float* __restrict__ w1,
                            const float* __restrict__ b1, const float* __restrict__ w2,
                            const float* __restrict__ b2, float* __restrict__ out) {
    __shared__ float gr[256];
    __shared__ float z[128];
    int b = blockIdx.x, t = threadIdx.x;
    gr[t] = g[b * 256 + t];
    gr[t + 128] = g[b * 256 + 128 + t];
    __syncthreads();
    float acc = b1[t];
    for (int k = 0; k < 256; k++) acc += gr[k] * w1[k * 128 + t];
    z[t] = fmaxf(acc, 0.0f);
    __syncthreads();
    if (t < 12) {
        float o = b2[t];
        for (int k = 0; k < 128; k++) o += z[k] * w2[k * 12 + t];
        out[b * 12 + t] = o;
    }
}

// ---------------- launch ----------------

extern "C" void kernel_launch(void* const* d_in, const int* in_sizes, int n_in,
                              void* d_out, int out_size, void* d_ws, size_t ws_size,
                              hipStream_t stream) {
    const float* x      = (const float*)d_in[0];
    const int*   ei     = (const int*)d_in[1];
    const int*   batch  = (const int*)d_in[2];
    const float* node_w = (const float*)d_in[3];
    const float* node_b = (const float*)d_in[4];
    const float* conv_w = (const float*)d_in[5];
    const float* conv_b = (const float*)d_in[6];
    const float* bn_g   = (const float*)d_in[7];
    const float* bn_b   = (const float*)d_in[8];
    const float* hw1    = (const float*)d_in[9];
    const float* hb1    = (const float*)d_in[10];
    const float* hw2    = (const float*)d_in[11];
    const float* hb2    = (const float*)d_in[12];
    float* out = (float*)d_out;

    const int N = in_sizes[2];
    const int E = in_sizes[1] / 2;
    const int H = 256;
    const float inv_n = 1.0f / (float)N;

    char* base = (char*)d_ws;
    size_t off = 0;
    auto alloc = [&](size_t bytes) -> void* {
        off = (off + 255) & ~(size_t)255;
        void* p = base + off;
        off += bytes;
        return p;
    };
    unsigned short* xs  = (unsigned short*)alloc((size_t)(N + 1) * 64 * 2);   // +1 zero row
    unsigned short* y96 = (unsigned short*)alloc((size_t)N * 96 * 2);
    unsigned short* w96 = (unsigned short*)alloc((size_t)256 * 96 * 2);
    unsigned short* h   = (unsigned short*)alloc((size_t)N * H * 2);
    unsigned short* hws = (unsigned short*)alloc((size_t)(N + 1) * H * 2);    // +1 zero row
    unsigned short* agg = (unsigned short*)alloc((size_t)N * H * 2);
    unsigned short* cwT = (unsigned short*)alloc((size_t)3 * H * H * 2);
    // contiguous zero region: cnt | fill | sdis | stats
    int* zero_region = (int*)alloc(((size_t)3 * N + 512) * 4);
    int* cnt      = zero_region;
    int* fill     = zero_region + N;
    float* sdis   = (float*)(zero_region + 2 * N);
    float* stats  = (float*)(zero_region + 3 * N);
    int* rowstart = (int*)alloc((size_t)(N + 1) * 4);
    int* scanbuf  = (int*)alloc((size_t)N * 4);
    int* bsum     = (int*)alloc(1024);
    int* boff     = (int*)alloc(1024);
    int* eidx     = (int*)alloc((size_t)(E + 64) * 4);  // +64 pad
    float* dis    = (float*)alloc((size_t)N * 4);
    float* gpool  = (float*)alloc(64 * H * 4);

    const int* row = ei;
    const int* col = ei + E;

    hipMemsetAsync(zero_region, 0, ((size_t)3 * N + 512) * 4, stream);
    hipMemsetAsync(gpool, 0, 64 * H * 4, stream);

    prep_kernel<<<dim3(3 * H * H / 256 + 1), 256, 0, stream>>>(
        conv_w, cwT, hws + (size_t)N * H, xs + (size_t)N * 64);
    wfuse_kernel<<<dim3(256), 128, 0, stream>>>(node_w, node_b, conv_w, w96);

    deg_kernel<<<dim3((E + 255) / 256), 256, 0, stream>>>(col, cnt, E);
    int nb = (N + 511) / 512;
    scan1_kernel<<<dim3(nb), 512, 0, stream>>>(cnt, scanbuf, bsum, dis, N);
    scan2_kernel<<<dim3(1), 128, 0, stream>>>(bsum, boff, nb);
    scan3_kernel<<<dim3((N + 255) / 256), 256, 0, stream>>>(scanbuf, boff, rowstart, N);
    scatter_kernel<<<dim3((E + 255) / 256), 256, 0, stream>>>(row, col, rowstart, fill, eidx,
                                                              dis, sdis, E);
    xs_kernel<<<dim3((N * 64 / 4 + 255) / 256), 256, 0, stream>>>(x, dis, xs, N * 64 / 4);

    // layer 1: aggregate xs -> y96, then single K=96 GEMM (bias = conv_b[0])
    aggx_kernel<<<dim3((N + 15) / 16), 256, 0, stream>>>(xs, rowstart, eidx, dis, sdis, y96, N);
    dim3 gg((N + 127) / 128, H / 128);
    gemm_bt_kernel<<<gg, 256, 0, stream>>>(y96, w96, agg, conv_b, nullptr, nullptr, N, 96, H);
    stats_kernel<<<dim3((N + 31) / 32), 256, 0, stream>>>(agg, stats, N);
    elem_kernel<<<dim3((int)(((size_t)N * H / 4 + 255) / 256)), 256, 0, stream>>>(
        agg, stats, bn_g, bn_b, h, inv_n, (size_t)N * H);

    // layers 2-3
    for (int l = 1; l < 3; l++) {
        gemm_bt_kernel<<<gg, 256, 0, stream>>>(h, cwT + (size_t)l * H * H, hws, nullptr, dis,
                                               stats, N, H, H);
        agg_kernel<<<dim3((N + 15) / 16), 256, 0, stream>>>(hws, rowstart, eidx, dis,
                                                            conv_b + l * H, agg, stats, N);
        elem_kernel<<<dim3((int)(((size_t)N * H / 4 + 255) / 256)), 256, 0, stream>>>(
            agg, stats, bn_g + l * H, bn_b + l * H, h, inv_n, (size_t)N * H);
    }

    pool_kernel<<<dim3((N + 31) / 32), 256, 0, stream>>>(h, batch, gpool, N);
    head_kernel<<<dim3(64), 128, 0, stream>>>(gpool, hw1, hb1, hw2, hb2, out);
}

// Round 10
// 517.151 us; speedup vs baseline: 5.7486x; 1.1126x over previous
//
#include <hip/hip_runtime.h>
#include <stdint.h>

#define AS1 __attribute__((address_space(1)))
#define AS3 __attribute__((address_space(3)))

typedef __bf16 bf16x8 __attribute__((ext_vector_type(8)));
typedef float f32x4 __attribute__((ext_vector_type(4)));

__device__ __forceinline__ float bf2f(unsigned short u) {
    return __uint_as_float(((unsigned)u) << 16);
}
__device__ __forceinline__ unsigned short f2bf(float f) {
    unsigned u = __float_as_uint(f);
    unsigned r = u + 0x7fffu + ((u >> 16) & 1u);  // RNE
    return (unsigned short)(r >> 16);
}
__device__ __forceinline__ void unpack4(uint2 u, float& a, float& b, float& c, float& d) {
    a = __uint_as_float(u.x << 16);
    b = __uint_as_float(u.x & 0xffff0000u);
    c = __uint_as_float(u.y << 16);
    d = __uint_as_float(u.y & 0xffff0000u);
}
__device__ __forceinline__ uint2 pack4(float a, float b, float c, float d) {
    uint2 o;
    o.x = (unsigned)f2bf(a) | ((unsigned)f2bf(b) << 16);
    o.y = (unsigned)f2bf(c) | ((unsigned)f2bf(d) << 16);
    return o;
}

// ---------------- prep: cwT transpose | zero pad rows | wfuse, one packed grid ----------------
// blocks [0,768): cwT; block 768: zero rows; blocks [769,1025): wfuse column n = b-769.

__global__ void prep_kernel(const float* __restrict__ cw, unsigned short* __restrict__ cwT,
                            unsigned short* __restrict__ hz, unsigned short* __restrict__ xz,
                            const float* __restrict__ nw, const float* __restrict__ nb,
                            unsigned short* __restrict__ w96) {
    __shared__ float colv[256];
    int b = blockIdx.x, t = threadIdx.x;
    if (b < 768) {
        int idx = b * 256 + t;  // over 3*256*256
        int l = idx >> 16, rem = idx & 65535;
        int k = rem >> 8, n = rem & 255;
        cwT[(l << 16) + (n << 8) + k] = f2bf(cw[idx]);
    } else if (b == 768) {
        hz[t] = 0;
        if (t < 64) xz[t] = 0;
    } else {
        // W96T[n][k]: k<64 -> (node_w @ conv_w0)[k,n]; k==64 -> (node_b @ conv_w0)[n]; else 0
        int n = b - 769;
        colv[t] = cw[t * 256 + n];  // conv_w layer 0 column n
        __syncthreads();
        if (t < 64) {
            float acc = 0.0f;
            for (int j = 0; j < 256; j++) acc += nw[t * 256 + j] * colv[j];
            w96[n * 96 + t] = f2bf(acc);
        } else if (t == 64) {
            float acc = 0.0f;
            for (int j = 0; j < 256; j++) acc += nb[j] * colv[j];
            w96[n * 96 + t] = f2bf(acc);
        } else if (t < 96) {
            w96[n * 96 + t] = 0;
        }
    }
}

// ---------------- degree / CSR build ----------------

__global__ void deg_kernel(const int* __restrict__ col, int* __restrict__ cnt, int E) {
    int e = blockIdx.x * 256 + threadIdx.x;
    if (e < E) atomicAdd(&cnt[col[e]], 1);
}

__global__ void scan1_kernel(const int* __restrict__ cnt, int* __restrict__ scanbuf,
                             int* __restrict__ bsum, float* __restrict__ dis, int N) {
    __shared__ int s[512];
    int i = blockIdx.x * 512 + threadIdx.x;
    int c = (i < N) ? cnt[i] : 0;
    if (i < N) dis[i] = rsqrtf((float)c + 1.0f);  // +1 self-loop
    s[threadIdx.x] = c;
    __syncthreads();
    for (int off = 1; off < 512; off <<= 1) {
        int t = (threadIdx.x >= off) ? s[threadIdx.x - off] : 0;
        __syncthreads();
        s[threadIdx.x] += t;
        __syncthreads();
    }
    if (i < N) scanbuf[i] = s[threadIdx.x];
    if (threadIdx.x == 511) bsum[blockIdx.x] = s[511];
}

__global__ void scan2_kernel(const int* __restrict__ bsum, int* __restrict__ boff, int nb) {
    __shared__ int s[128];
    int t = threadIdx.x;
    int v = (t < nb) ? bsum[t] : 0;
    s[t] = v;
    __syncthreads();
    for (int off = 1; off < 128; off <<= 1) {
        int u = (t >= off) ? s[t - off] : 0;
        __syncthreads();
        s[t] += u;
        __syncthreads();
    }
    if (t < nb) boff[t] = s[t] - v;  // exclusive
}

__global__ void scan3_kernel(const int* __restrict__ scanbuf, const int* __restrict__ boff,
                             int* __restrict__ rowstart, int N) {
    int i = blockIdx.x * 256 + threadIdx.x;
    if (i < N) rowstart[i + 1] = scanbuf[i] + boff[i >> 9];
    if (i == 0) rowstart[0] = 0;
}

// scatter edges into CSR (atomicSub on warm cnt; counts dead after scan);
// also accumulate sdis[v] = sum of dis[src] over in-edges
__global__ void scatter_kernel(const int* __restrict__ row, const int* __restrict__ col,
                               const int* __restrict__ rowstart, int* __restrict__ cnt,
                               int* __restrict__ eidx, const float* __restrict__ dis,
                               float* __restrict__ sdis, int E) {
    int e = blockIdx.x * 256 + threadIdx.x;
    if (e < E) {
        int c = col[e];
        int r = row[e];
        int old = atomicSub(&cnt[c], 1);
        eidx[rowstart[c] + old - 1] = r;
        atomicAdd(&sdis[c], dis[r]);
    }
}

// xs[u] = dis[u] * x[u]  (bf16, N x 64)
__global__ void xs_kernel(const float* __restrict__ x, const float* __restrict__ dis,
                          unsigned short* __restrict__ xs, int total4) {
    int i4 = blockIdx.x * 256 + threadIdx.x;
    if (i4 < total4) {
        int i = i4 * 4;
        float d = dis[i >> 6];
        float4 v = *reinterpret_cast<const float4*>(x + i);
        *reinterpret_cast<uint2*>(xs + i) = pack4(d * v.x, d * v.y, d * v.z, d * v.w);
    }
}

// ---------------- GEMM (m97 recipe): C[M,Nc] = A[M,K] * BT[Nc,K]^T ----------------
// bf16 in, fp32 MFMA accumulate, bf16 out; optional per-row scale[mr];
// stats_accum: accumulate per-column sum/sumsq of C into stats (layer-1 BN);
// stats_clear: zero stats[512] (block 0,0) for the NEXT layer's agg.

__global__ __launch_bounds__(256)
void gemm_bt_kernel(const unsigned short* __restrict__ A, const unsigned short* __restrict__ BT,
                    unsigned short* __restrict__ C, const float* __restrict__ scale,
                    float* __restrict__ stats_accum, float* __restrict__ stats_clear,
                    int M, int K, int Nc) {
    __shared__ unsigned short As[128 * 32];
    __shared__ unsigned short Bs[128 * 32];
    __shared__ float stLS[256];

    if (stats_clear && blockIdx.x == 0 && blockIdx.y == 0) {
        stats_clear[threadIdx.x] = 0.0f;
        stats_clear[256 + threadIdx.x] = 0.0f;
    }
    if (stats_accum) stLS[threadIdx.x] = 0.0f;

    const int lane = threadIdx.x & 63;
    const int wave = threadIdx.x >> 6;
    const int wm = wave >> 1, wn = wave & 1;
    const int r = lane & 15, q = lane >> 4;
    const int m0b = blockIdx.x * 128;
    const int n0b = blockIdx.y * 128;
    const int m0 = m0b + wm * 64;
    const int n0 = n0b + wn * 64;

    f32x4 acc[4][4] = {};

    for (int k0 = 0; k0 < K; k0 += 32) {
        __syncthreads();  // previous tile consumed
#pragma unroll
        for (int j = 0; j < 2; j++) {
            int s = threadIdx.x + j * 256;        // 512 slots of 16 B
            int row = s >> 2, kp = s & 3;
            int mr = m0b + row;
            if (mr >= M) mr = M - 1;
            const unsigned short* ga = A + (size_t)mr * K + k0 + kp * 8;
            __builtin_amdgcn_global_load_lds((const AS1 void*)ga, (AS3 void*)(As + s * 8), 16, 0, 0);
            int nr = n0b + row;                    // Nc is a multiple of 128
            const unsigned short* gb = BT + (size_t)nr * K + k0 + kp * 8;
            __builtin_amdgcn_global_load_lds((const AS1 void*)gb, (AS3 void*)(Bs + s * 8), 16, 0, 0);
        }
        __syncthreads();  // drains vmcnt -> LDS ready

        bf16x8 a[4], b[4];
#pragma unroll
        for (int i = 0; i < 4; i++)
            a[i] = *reinterpret_cast<const bf16x8*>(As + ((wm * 64 + i * 16 + r) * 32 + q * 8));
#pragma unroll
        for (int j = 0; j < 4; j++)
            b[j] = *reinterpret_cast<const bf16x8*>(Bs + ((wn * 64 + j * 16 + r) * 32 + q * 8));
#pragma unroll
        for (int i = 0; i < 4; i++)
#pragma unroll
            for (int j = 0; j < 4; j++)
                acc[i][j] = __builtin_amdgcn_mfma_f32_16x16x32_bf16(a[i], b[j], acc[i][j], 0, 0, 0);
    }

    float psl[4] = {}, pql[4] = {};
#pragma unroll
    for (int i = 0; i < 4; i++) {
#pragma unroll
        for (int t = 0; t < 4; t++) {
            int mr = m0 + i * 16 + q * 4 + t;  // C/D: row = q*4+reg, col = lane&15
            if (mr < M) {
                float rs = scale ? scale[mr] : 1.0f;
#pragma unroll
                for (int j = 0; j < 4; j++) {
                    int nc = n0 + j * 16 + r;
                    float v = acc[i][j][t] * rs;
                    C[(size_t)mr * Nc + nc] = f2bf(v);
                    psl[j] += v;
                    pql[j] += v * v;
                }
            }
        }
    }

    if (stats_accum) {
        __syncthreads();  // stLS zeroed by all threads
#pragma unroll
        for (int j = 0; j < 4; j++) {
            int c = wn * 64 + j * 16 + r;
            atomicAdd(&stLS[c], psl[j]);
            atomicAdd(&stLS[128 + c], pql[j]);
        }
        __syncthreads();
        if (threadIdx.x < 128) {
            atomicAdd(&stats_accum[n0b + threadIdx.x], stLS[threadIdx.x]);
            atomicAdd(&stats_accum[256 + n0b + threadIdx.x], stLS[128 + threadIdx.x]);
        }
    }
}

// ---------------- aggx: layer-1 aggregation over xs (64 feats) -> y96 ----------------
// Triple-buffered; y row = [ dis_v*(xs_v + sum xs_src) (64) | s_v (1) | 0 pad to 96 ].

__global__ __launch_bounds__(256)
void aggx_kernel(const unsigned short* __restrict__ xs, const int* __restrict__ rowstart,
                 const int* __restrict__ eidx, const float* __restrict__ dis,
                 const float* __restrict__ sdis, unsigned short* __restrict__ y96, int N) {
    const int lane = threadIdx.x & 63;
    const int wave = threadIdx.x >> 6;
    const int slot = lane >> 3;       // 8 edges per round
    const int fl = (lane & 7) * 8;    // 8 features per lane

    const int vb = __builtin_amdgcn_readfirstlane(blockIdx.x * 16 + wave * 4);

    int rs[5];
#pragma unroll
    for (int s = 0; s < 5; s++) rs[s] = rowstart[min(vb + s, N)];
    int js[4], de[4];
    float dvv[4], svv[4];
#pragma unroll
    for (int s = 0; s < 4; s++) {
        js[s] = rs[s];
        bool ok = (vb + s) < N;
        de[s] = ok ? (rs[s + 1] - rs[s]) : 0;
        float dv = ok ? dis[vb + s] : 0.0f;
        dvv[s] = dv;
        svv[s] = ok ? (dv * (dv + sdis[vb + s])) : 0.0f;
    }

    int idx0 = (lane < de[0]) ? eidx[js[0] + lane] : N;
    int idx1 = (lane < de[1]) ? eidx[js[1] + lane] : N;
    int idx2 = (lane < de[2]) ? eidx[js[2] + lane] : N;
    int idx3 = (lane < de[3]) ? eidx[js[3] + lane] : N;

    uint4 sf[4];
#pragma unroll
    for (int s = 0; s < 4; s++)
        sf[s] = *reinterpret_cast<const uint4*>(xs + (size_t)min(vb + s, N) * 64 + fl);

    uint4 rA[2], rB[2], rC[2];

    auto issue = [&](int myidx, uint4 (&rr)[2]) {
#pragma unroll
        for (int ro = 0; ro < 2; ro++) {
            int u = __shfl(myidx, ro * 8 + slot);
            rr[ro] = *reinterpret_cast<const uint4*>(xs + (size_t)u * 64 + fl);
        }
    };

    auto consume = [&](int s, int js_s, int d, float dv, float sv, int myidx, uint4 (&rr)[2]) {
        float a[8] = {};
#pragma unroll
        for (int ro = 0; ro < 2; ro++) {
            float x0, x1, x2, x3;
            unpack4(make_uint2(rr[ro].x, rr[ro].y), x0, x1, x2, x3);
            a[0] += x0; a[1] += x1; a[2] += x2; a[3] += x3;
            unpack4(make_uint2(rr[ro].z, rr[ro].w), x0, x1, x2, x3);
            a[4] += x0; a[5] += x1; a[6] += x2; a[7] += x3;
        }
        int cnp = min(64, (d + 15) & ~15);
        for (int t = 16; t < cnp; t += 16) {
#pragma unroll
            for (int ro = 0; ro < 2; ro++) {
                int u = __shfl(myidx, t + ro * 8 + slot);
                rr[ro] = *reinterpret_cast<const uint4*>(xs + (size_t)u * 64 + fl);
            }
#pragma unroll
            for (int ro = 0; ro < 2; ro++) {
                float x0, x1, x2, x3;
                unpack4(make_uint2(rr[ro].x, rr[ro].y), x0, x1, x2, x3);
                a[0] += x0; a[1] += x1; a[2] += x2; a[3] += x3;
                unpack4(make_uint2(rr[ro].z, rr[ro].w), x0, x1, x2, x3);
                a[4] += x0; a[5] += x1; a[6] += x2; a[7] += x3;
            }
        }
        for (int base = 64; base < d; base += 64) {
            int mi = (base + lane < d) ? eidx[js_s + base + lane] : N;
            int cn2 = min(64, d - base);
            int cnp2 = (cn2 + 15) & ~15;
            for (int t = 0; t < cnp2; t += 16) {
#pragma unroll
                for (int ro = 0; ro < 2; ro++) {
                    int u = __shfl(mi, t + ro * 8 + slot);
                    rr[ro] = *reinterpret_cast<const uint4*>(xs + (size_t)u * 64 + fl);
                }
#pragma unroll
                for (int ro = 0; ro < 2; ro++) {
                    float x0, x1, x2, x3;
                    unpack4(make_uint2(rr[ro].x, rr[ro].y), x0, x1, x2, x3);
                    a[0] += x0; a[1] += x1; a[2] += x2; a[3] += x3;
                    unpack4(make_uint2(rr[ro].z, rr[ro].w), x0, x1, x2, x3);
                    a[4] += x0; a[5] += x1; a[6] += x2; a[7] += x3;
                }
            }
        }
#pragma unroll
        for (int j = 0; j < 8; j++) {
            a[j] += __shfl_xor(a[j], 8);
            a[j] += __shfl_xor(a[j], 16);
            a[j] += __shfl_xor(a[j], 32);
        }
        if ((vb + s) < N) {
            if (lane < 8) {
                float x0, x1, x2, x3;
                unpack4(make_uint2(sf[s].x, sf[s].y), x0, x1, x2, x3);
                a[0] += x0; a[1] += x1; a[2] += x2; a[3] += x3;
                unpack4(make_uint2(sf[s].z, sf[s].w), x0, x1, x2, x3);
                a[4] += x0; a[5] += x1; a[6] += x2; a[7] += x3;
                uint2 lo = pack4(dv * a[0], dv * a[1], dv * a[2], dv * a[3]);
                uint2 hi = pack4(dv * a[4], dv * a[5], dv * a[6], dv * a[7]);
                *reinterpret_cast<uint4*>(y96 + (size_t)(vb + s) * 96 + fl) =
                    make_uint4(lo.x, lo.y, hi.x, hi.y);
            } else if (lane < 12) {
                unsigned sx = (lane == 8) ? (unsigned)f2bf(sv) : 0u;
                *reinterpret_cast<uint4*>(y96 + (size_t)(vb + s) * 96 + 64 + (lane - 8) * 8) =
                    make_uint4(sx, 0u, 0u, 0u);
            }
        }
    };

    issue(idx0, rA);
    issue(idx1, rB);
    issue(idx2, rC);
    consume(0, js[0], de[0], dvv[0], svv[0], idx0, rA);
    issue(idx3, rA);
    consume(1, js[1], de[1], dvv[1], svv[1], idx1, rB);
    consume(2, js[2], de[2], dvv[2], svv[2], idx2, rC);
    consume(3, js[3], de[3], dvv[3], svv[3], idx3, rA);
}

// ---------------- aggregation layers 2-3 (R4 ping-pong) + fused BN stats ----------------
// conv_b dropped: BatchNorm (training mode) cancels any per-feature constant exactly.

__global__ __launch_bounds__(256)
void agg_kernel(const unsigned short* __restrict__ hws, const int* __restrict__ rowstart,
                const int* __restrict__ eidx, const float* __restrict__ dis,
                unsigned short* __restrict__ agg, float* __restrict__ stats, int N) {
    __shared__ float s_sum[4][256];
    __shared__ float s_sq[4][256];
    const int lane = threadIdx.x & 63;
    const int wave = threadIdx.x >> 6;
    const int sub = lane >> 5;         // edge parity
    const int fl = (lane & 31) * 8;    // feature base (8 features per lane)

    const int vb = __builtin_amdgcn_readfirstlane(blockIdx.x * 16 + wave * 4);

    int rs[5];
#pragma unroll
    for (int s = 0; s < 5; s++) rs[s] = rowstart[min(vb + s, N)];
    int js[4], de[4];
    float dvv[4];
#pragma unroll
    for (int s = 0; s < 4; s++) {
        js[s] = rs[s];
        de[s] = (vb + s < N) ? (rs[s + 1] - rs[s]) : 0;
        dvv[s] = (vb + s < N) ? dis[vb + s] : 0.0f;
    }

    int idx0 = (lane < de[0]) ? eidx[js[0] + lane] : N;
    int idx1 = (lane < de[1]) ? eidx[js[1] + lane] : N;
    int idx2 = (lane < de[2]) ? eidx[js[2] + lane] : N;
    int idx3 = (lane < de[3]) ? eidx[js[3] + lane] : N;
    uint4 sf[4];
#pragma unroll
    for (int s = 0; s < 4; s++)
        sf[s] = *reinterpret_cast<const uint4*>(hws + (size_t)min(vb + s, N) * 256 + fl);

    float ps[8] = {}, pq[8] = {};

    uint4 rA[8], rB[8];

    auto issue = [&](int myidx, uint4 (&rr)[8]) {
#pragma unroll
        for (int k = 0; k < 8; k++) {
            int u = __shfl(myidx, 2 * k + sub);
            rr[k] = *reinterpret_cast<const uint4*>(hws + (size_t)u * 256 + fl);
        }
    };

    auto consume = [&](int s, int js_s, int d, float dvs, int myidx, uint4 (&rr)[8]) {
        float a[8] = {};
#pragma unroll
        for (int k = 0; k < 8; k++) {
            float x0, x1, x2, x3;
            unpack4(make_uint2(rr[k].x, rr[k].y), x0, x1, x2, x3);
            a[0] += x0; a[1] += x1; a[2] += x2; a[3] += x3;
            unpack4(make_uint2(rr[k].z, rr[k].w), x0, x1, x2, x3);
            a[4] += x0; a[5] += x1; a[6] += x2; a[7] += x3;
        }
        int cnp = min(64, (d + 15) & ~15);
        for (int t = 16; t < cnp; t += 16) {
#pragma unroll
            for (int k = 0; k < 8; k++) {
                int u = __shfl(myidx, t + 2 * k + sub);
                rr[k] = *reinterpret_cast<const uint4*>(hws + (size_t)u * 256 + fl);
            }
#pragma unroll
            for (int k = 0; k < 8; k++) {
                float x0, x1, x2, x3;
                unpack4(make_uint2(rr[k].x, rr[k].y), x0, x1, x2, x3);
                a[0] += x0; a[1] += x1; a[2] += x2; a[3] += x3;
                unpack4(make_uint2(rr[k].z, rr[k].w), x0, x1, x2, x3);
                a[4] += x0; a[5] += x1; a[6] += x2; a[7] += x3;
            }
        }
        for (int base = 64; base < d; base += 64) {
            int mi = (base + lane < d) ? eidx[js_s + base + lane] : N;
            int cn2 = min(64, d - base);
            int cnp2 = (cn2 + 15) & ~15;
            for (int t = 0; t < cnp2; t += 16) {
#pragma unroll
                for (int k = 0; k < 8; k++) {
                    int u = __shfl(mi, t + 2 * k + sub);
                    rr[k] = *reinterpret_cast<const uint4*>(hws + (size_t)u * 256 + fl);
                }
#pragma unroll
                for (int k = 0; k < 8; k++) {
                    float x0, x1, x2, x3;
                    unpack4(make_uint2(rr[k].x, rr[k].y), x0, x1, x2, x3);
                    a[0] += x0; a[1] += x1; a[2] += x2; a[3] += x3;
                    unpack4(make_uint2(rr[k].z, rr[k].w), x0, x1, x2, x3);
                    a[4] += x0; a[5] += x1; a[6] += x2; a[7] += x3;
                }
            }
        }
#pragma unroll
        for (int j = 0; j < 8; j++) a[j] += __shfl_xor(a[j], 32);
        float x0, x1, x2, x3;
        unpack4(make_uint2(sf[s].x, sf[s].y), x0, x1, x2, x3);
        a[0] += x0; a[1] += x1; a[2] += x2; a[3] += x3;
        unpack4(make_uint2(sf[s].z, sf[s].w), x0, x1, x2, x3);
        a[4] += x0; a[5] += x1; a[6] += x2; a[7] += x3;
        float g[8];
#pragma unroll
        for (int j = 0; j < 8; j++) g[j] = dvs * a[j];
        if (vb + s < N && sub == 0) {
            uint2 lo = pack4(g[0], g[1], g[2], g[3]);
            uint2 hi = pack4(g[4], g[5], g[6], g[7]);
            *reinterpret_cast<uint4*>(agg + (size_t)(vb + s) * 256 + fl) =
                make_uint4(lo.x, lo.y, hi.x, hi.y);
#pragma unroll
            for (int j = 0; j < 8; j++) { ps[j] += g[j]; pq[j] += g[j] * g[j]; }
        }
    };

    issue(idx0, rA);
    issue(idx1, rB);
    consume(0, js[0], de[0], dvv[0], idx0, rA);
    issue(idx2, rA);
    consume(1, js[1], de[1], dvv[1], idx1, rB);
    issue(idx3, rB);
    consume(2, js[2], de[2], dvv[2], idx2, rA);
    consume(3, js[3], de[3], dvv[3], idx3, rB);

    if (sub == 0) {
#pragma unroll
        for (int j = 0; j < 8; j++) {
            s_sum[wave][fl + j] = ps[j];
            s_sq[wave][fl + j] = pq[j];
        }
    }
    __syncthreads();

    int f = threadIdx.x;
    float ts = s_sum[0][f] + s_sum[1][f] + s_sum[2][f] + s_sum[3][f];
    float tq = s_sq[0][f] + s_sq[1][f] + s_sq[2][f] + s_sq[3][f];
    atomicAdd(&stats[f], ts);
    atomicAdd(&stats[256 + f], tq);
}

// ---------------- elem: BN affine (inline from stats) + ReLU -> bf16 h (layers 1-2) ----------------

__global__ __launch_bounds__(256)
void elem_kernel(const unsigned short* __restrict__ agg, const float* __restrict__ stats,
                 const float* __restrict__ bng, const float* __restrict__ bnb,
                 unsigned short* __restrict__ h, float inv_n, size_t total) {
    __shared__ float ssL[512];
    {
        int f = threadIdx.x;
        float mean = stats[f] * inv_n;
        float var = stats[256 + f] * inv_n - mean * mean;
        float sc = bng[f] * rsqrtf(var + 1e-5f);
        ssL[f] = sc;
        ssL[256 + f] = bnb[f] - mean * sc;
    }
    __syncthreads();
    size_t i = ((size_t)blockIdx.x * 256 + threadIdx.x) * 4;
    if (i < total) {
        float a0, a1, a2, a3;
        unpack4(*reinterpret_cast<const uint2*>(agg + i), a0, a1, a2, a3);
        int f = (int)(i & 255);
        float r0 = fmaxf(a0 * ssL[f] + ssL[256 + f], 0.0f);
        float r1 = fmaxf(a1 * ssL[f + 1] + ssL[256 + f + 1], 0.0f);
        float r2 = fmaxf(a2 * ssL[f + 2] + ssL[256 + f + 2], 0.0f);
        float r3 = fmaxf(a3 * ssL[f + 3] + ssL[256 + f + 3], 0.0f);
        *reinterpret_cast<uint2*>(h + i) = pack4(r0, r1, r2, r3);
    }
}

// ---------------- elem_pool: layer-3 BN+ReLU fused directly into global_add_pool ----------------
// Reads agg, never materializes h. 32 rows/block; batch sorted -> run-length + atomics.

__global__ __launch_bounds__(256)
void elem_pool_kernel(const unsigned short* __restrict__ agg, const float* __restrict__ stats,
                      const float* __restrict__ bng, const float* __restrict__ bnb,
                      const int* __restrict__ batch, float* __restrict__ g,
                      float inv_n, int N) {
    __shared__ float ssL[512];
    __shared__ int sb[32];
    int f = threadIdx.x;
    {
        float mean = stats[f] * inv_n;
        float var = stats[256 + f] * inv_n - mean * mean;
        float sc = bng[f] * rsqrtf(var + 1e-5f);
        ssL[f] = sc;
        ssL[256 + f] = bnb[f] - mean * sc;
    }
    int r0 = blockIdx.x * 32;
    int rows = min(32, N - r0);
    if (f < 32) sb[f] = (r0 + f < N) ? batch[r0 + f] : -1;
    __syncthreads();
    float sc = ssL[f], sh = ssL[256 + f];
    float acc = 0.0f;
    int cur = sb[0];
    for (int t = 0; t < rows; t++) {
        int b = sb[t];
        if (b != cur) {
            atomicAdd(&g[cur * 256 + f], acc);
            acc = 0.0f;
            cur = b;
        }
        float v = bf2f(agg[(size_t)(r0 + t) * 256 + f]);
        acc += fmaxf(v * sc + sh, 0.0f);
    }
    atomicAdd(&g[cur * 256 + f], acc);
}

// ---------------- head MLP: relu(g@w1+b1)@w2+b2 ----------------

__global__ void head_kernel(const float* __restrict__ g, const float* __restrict__ w1,
                            const float* __restrict__ b1, const float* __restrict__ w2,
                            const float* __restrict__ b2, float* __restrict__ out) {
    __shared__ float gr[256];
    __shared__ float z[128];
    int b = blockIdx.x, t = threadIdx.x;
    gr[t] = g[b * 256 + t];
    gr[t + 128] = g[b * 256 + 128 + t];
    __syncthreads();
    float acc = b1[t];
    for (int k = 0; k < 256; k++) acc += gr[k] * w1[k * 128 + t];
    z[t] = fmaxf(acc, 0.0f);
    __syncthreads();
    if (t < 12) {
        float o = b2[t];
        for (int k = 0; k < 128; k++) o += z[k] * w2[k * 12 + t];
        out[b * 12 + t] = o;
    }
}

// ---------------- launch ----------------

extern "C" void kernel_launch(void* const* d_in, const int* in_sizes, int n_in,
                              void* d_out, int out_size, void* d_ws, size_t ws_size,
                              hipStream_t stream) {
    const float* x      = (const float*)d_in[0];
    const int*   ei     = (const int*)d_in[1];
    const int*   batch  = (const int*)d_in[2];
    const float* node_w = (const float*)d_in[3];
    const float* node_b = (const float*)d_in[4];
    const float* conv_w = (const float*)d_in[5];
    const float* bn_g   = (const float*)d_in[7];
    const float* bn_b   = (const float*)d_in[8];
    const float* hw1    = (const float*)d_in[9];
    const float* hb1    = (const float*)d_in[10];
    const float* hw2    = (const float*)d_in[11];
    const float* hb2    = (const float*)d_in[12];
    float* out = (float*)d_out;

    const int N = in_sizes[2];
    const int E = in_sizes[1] / 2;
    const int H = 256;
    const float inv_n = 1.0f / (float)N;

    char* base = (char*)d_ws;
    size_t off = 0;
    auto alloc = [&](size_t bytes) -> void* {
        off = (off + 255) & ~(size_t)255;
        void* p = base + off;
        off += bytes;
        return p;
    };
    unsigned short* xs  = (unsigned short*)alloc((size_t)(N + 1) * 64 * 2);   // +1 zero row
    unsigned short* y96 = (unsigned short*)alloc((size_t)N * 96 * 2);
    unsigned short* w96 = (unsigned short*)alloc((size_t)256 * 96 * 2);
    unsigned short* h   = (unsigned short*)alloc((size_t)N * H * 2);
    unsigned short* hws = (unsigned short*)alloc((size_t)(N + 1) * H * 2);    // +1 zero row
    unsigned short* agg = (unsigned short*)alloc((size_t)N * H * 2);
    unsigned short* cwT = (unsigned short*)alloc((size_t)3 * H * H * 2);
    // contiguous zero region: cnt | sdis | stats | gpool
    int* zero_region = (int*)alloc(((size_t)2 * N + 512 + 64 * H) * 4);
    int* cnt      = zero_region;
    float* sdis   = (float*)(zero_region + N);
    float* stats  = (float*)(zero_region + 2 * N);
    float* gpool  = (float*)(zero_region + 2 * N + 512);
    int* rowstart = (int*)alloc((size_t)(N + 1) * 4);
    int* scanbuf  = (int*)alloc((size_t)N * 4);
    int* bsum     = (int*)alloc(1024);
    int* boff     = (int*)alloc(1024);
    int* eidx     = (int*)alloc((size_t)(E + 64) * 4);
    float* dis    = (float*)alloc((size_t)N * 4);

    const int* row = ei;
    const int* col = ei + E;

    hipMemsetAsync(zero_region, 0, ((size_t)2 * N + 512 + 64 * H) * 4, stream);

    // cwT transpose + zero pad rows + w96 fuse, one packed grid
    prep_kernel<<<dim3(768 + 1 + 256), 256, 0, stream>>>(
        conv_w, cwT, hws + (size_t)N * H, xs + (size_t)N * 64, node_w, node_b, w96);

    deg_kernel<<<dim3((E + 255) / 256), 256, 0, stream>>>(col, cnt, E);
    int nb = (N + 511) / 512;
    scan1_kernel<<<dim3(nb), 512, 0, stream>>>(cnt, scanbuf, bsum, dis, N);
    scan2_kernel<<<dim3(1), 128, 0, stream>>>(bsum, boff, nb);
    scan3_kernel<<<dim3((N + 255) / 256), 256, 0, stream>>>(scanbuf, boff, rowstart, N);
    scatter_kernel<<<dim3((E + 255) / 256), 256, 0, stream>>>(row, col, rowstart, cnt, eidx,
                                                              dis, sdis, E);
    xs_kernel<<<dim3((N * 64 / 4 + 255) / 256), 256, 0, stream>>>(x, dis, xs, N * 64 / 4);

    dim3 gg((N + 127) / 128, H / 128);
    size_t elem_blocks = ((size_t)N * H / 4 + 255) / 256;

    // layer 1: aggregate xs -> y96; K=96 GEMM with fused BN-stats accumulation
    aggx_kernel<<<dim3((N + 15) / 16), 256, 0, stream>>>(xs, rowstart, eidx, dis, sdis, y96, N);
    gemm_bt_kernel<<<gg, 256, 0, stream>>>(y96, w96, agg, nullptr, stats, nullptr, N, 96, H);
    elem_kernel<<<dim3((int)elem_blocks), 256, 0, stream>>>(agg, stats, bn_g, bn_b, h,
                                                            inv_n, (size_t)N * H);

    // layer 2
    gemm_bt_kernel<<<gg, 256, 0, stream>>>(h, cwT + (size_t)1 * H * H, hws, dis,
                                           nullptr, stats, N, H, H);
    agg_kernel<<<dim3((N + 15) / 16), 256, 0, stream>>>(hws, rowstart, eidx, dis, agg, stats, N);
    elem_kernel<<<dim3((int)elem_blocks), 256, 0, stream>>>(agg, stats, bn_g + H, bn_b + H, h,
                                                            inv_n, (size_t)N * H);

    // layer 3 (elem fused into pool; h never written)
    gemm_bt_kernel<<<gg, 256, 0, stream>>>(h, cwT + (size_t)2 * H * H, hws, dis,
                                           nullptr, stats, N, H, H);
    agg_kernel<<<dim3((N + 15) / 16), 256, 0, stream>>>(hws, rowstart, eidx, dis, agg, stats, N);
    elem_pool_kernel<<<dim3((N + 31) / 32), 256, 0, stream>>>(agg, stats, bn_g + 2 * H,
                                                              bn_b + 2 * H, batch, gpool,
                                                              inv_n, N);

    head_kernel<<<dim3(64), 128, 0, stream>>>(gpool, hw1, hb1, hw2, hb2, out);
}